// Round 12
// baseline (1532.559 us; speedup 1.0000x reference)
//
#include <hip/hip_runtime.h>
#include <hip/hip_bf16.h>
#include <math.h>

#define LAYERS 4
#define DMODEL 512
#define NH 8
#define DH 64
#define DFF 2048
#define NB 4
#define S_LEN 2048
#define MROWS 8192
#define CHUNK 64
#define NCHUNK 32            // S_LEN / CHUNK
#define ATT_EPS 1e-6f
#define LN_EPS 1e-5f
#define SEGSTRIDE (MROWS * DMODEL)   // 4194304 elems per q/k/v segment

typedef __attribute__((ext_vector_type(8))) short short8v;   // 8 bf16
typedef __attribute__((ext_vector_type(4))) float f32x4;

__device__ __forceinline__ float b2f(unsigned short u) {
    union { float f; unsigned u; } c; c.u = ((unsigned)u) << 16; return c.f;
}
__device__ __forceinline__ unsigned short f2b(float f) {
    union { float f; unsigned u; } c; c.f = f;
    unsigned r = c.u + 0x7FFFu + ((c.u >> 16) & 1u);
    return (unsigned short)(r >> 16);
}
__device__ __forceinline__ void gload16(const void* g, void* l) {
    __builtin_amdgcn_global_load_lds(
        (const __attribute__((address_space(1))) void*)g,
        (__attribute__((address_space(3))) void*)l, 16, 0, 0);
}
__device__ __forceinline__ float elu1f(float v) {
    return (v > 0.f) ? (v + 1.f) : __expf(v);
}
__device__ __forceinline__ float geluf(float v) {
    float u = 0.7978845608028654f * v * (1.f + 0.044715f * v * v);
    float th = 1.f - 2.f / (1.f + __expf(2.f * u));
    return 0.5f * v * (1.f + th);
}

// ---------------------------------------------------------------------------
// Wide-N bf16 MFMA GEMM for the fat GEMMs (qkv, W1): BM=128, BN=256, BK=32,
// 8 waves (2Mx4N) each owning 64x64. 2x24KB LDS buffers (48KB) -> 3 blocks/CU
// = 24 waves/CU. Per block-iter: LDS 64KB frag-reads + 24KB staging per
// 2.1 MFLOP (24 FLOP/byte, 1.5x R8's gemm8). Counted vmcnt(3) depth-1;
// (row>>1)&3 XOR slot swizzle both sides (R10-verified 0-conflict).
// ACT: 2=gelu (W1), 3=qkv-fused (segments of 512: seg<2 elu+1). bf16 out.
// ---------------------------------------------------------------------------
template <int ACT>
__global__ __launch_bounds__(512, 6) void gemmw(
    const unsigned short* __restrict__ A,
    const unsigned short* __restrict__ WT,
    const float* __restrict__ b0, const float* __restrict__ b1,
    const float* __restrict__ b2,
    unsigned short* __restrict__ Cbf,
    int M, int N, int K)
{
    __shared__ short S[2][12288];   // [A 128x32 | B 256x32] swizzled, 24KB/buf

    const int t = threadIdx.x;
    const int m0 = blockIdx.x * 128, n0 = blockIdx.y * 256;
    const int lane = t & 63, wid = t >> 6;
    const int wm = (wid >> 2) * 64;   // 2 M-bands of 64
    const int wn = (wid & 3) * 64;    // 4 N-bands of 64
    const int fr = lane & 15, kg = lane >> 4;

    // staging: unit u: row=u>>2, phys slot u&3, logical slot = phys^((row>>1)&3)
    // A: u = t (512 units, 128 rows). B: u = t, t+512 (1024 units, 256 rows).
    const unsigned short* gA;
    const unsigned short* gB0;
    const unsigned short* gB1;
    int loA, loB0, loB1;
    {
        const int rowA = t >> 2, spA = t & 3;
        gA = A + (size_t)(m0 + rowA) * K + (spA ^ ((rowA >> 1) & 3)) * 8;
        loA = t * 8;
        const int rB0 = t >> 2, sB0 = t & 3;
        gB0 = WT + (size_t)(n0 + rB0) * K + (sB0 ^ ((rB0 >> 1) & 3)) * 8;
        loB0 = 4096 + t * 8;
        const int u1 = t + 512;
        const int rB1 = u1 >> 2, sB1 = u1 & 3;
        gB1 = WT + (size_t)(n0 + rB1) * K + (sB1 ^ ((rB1 >> 1) & 3)) * 8;
        loB1 = 4096 + u1 * 8;
    }

    // fragment read offsets
    int aoff[4], boff[4];
#pragma unroll
    for (int m = 0; m < 4; ++m) {
        const int R = wm + m * 16 + fr;
        aoff[m] = R * 32 + ((kg ^ ((R >> 1) & 3)) << 3);
    }
#pragma unroll
    for (int n = 0; n < 4; ++n) {
        const int R = wn + n * 16 + fr;
        boff[n] = 4096 + R * 32 + ((kg ^ ((R >> 1) & 3)) << 3);
    }

    f32x4 acc[4][4];
#pragma unroll
    for (int m = 0; m < 4; ++m)
#pragma unroll
        for (int n = 0; n < 4; ++n) acc[m][n] = (f32x4){0.f, 0.f, 0.f, 0.f};

#define STAGE(b, kt) do {                                       \
    gload16(gA + (size_t)(kt) * 32, &S[b][loA]);                \
    gload16(gB0 + (size_t)(kt) * 32, &S[b][loB0]);              \
    gload16(gB1 + (size_t)(kt) * 32, &S[b][loB1]); } while (0)

    const int NT = K >> 5;
    STAGE(0, 0);

    for (int td = 0; td < NT; ++td) {
        const int b = td & 1;
        if (td + 1 < NT) {
            STAGE(b ^ 1, td + 1);
            __builtin_amdgcn_sched_barrier(0);
            asm volatile("s_waitcnt vmcnt(3)");   // tile td landed
        } else {
            __builtin_amdgcn_sched_barrier(0);
            asm volatile("s_waitcnt vmcnt(0)");
        }
        __builtin_amdgcn_sched_barrier(0);
        __builtin_amdgcn_s_barrier();
        __builtin_amdgcn_sched_barrier(0);

        short8v af[4], bf[4];
#pragma unroll
        for (int m = 0; m < 4; ++m) af[m] = *(const short8v*)&S[b][aoff[m]];
#pragma unroll
        for (int n = 0; n < 4; ++n) bf[n] = *(const short8v*)&S[b][boff[n]];

        asm volatile("s_waitcnt lgkmcnt(0)");
        __builtin_amdgcn_sched_barrier(0);
        __builtin_amdgcn_s_setprio(1);
#pragma unroll
        for (int m = 0; m < 4; ++m)
#pragma unroll
            for (int n = 0; n < 4; ++n)
                acc[m][n] = __builtin_amdgcn_mfma_f32_16x16x32_bf16(
                    af[m], bf[n], acc[m][n], 0, 0, 0);
        __builtin_amdgcn_s_setprio(0);

        __builtin_amdgcn_sched_barrier(0);
        __builtin_amdgcn_s_barrier();   // protect buf b before restage
    }
#undef STAGE

    // epilogue (BN=256 tile never straddles a 512-col segment)
    const int seg = (ACT == 3) ? (n0 >> 9) : 0;
    const float* bias = (ACT == 3) ? (seg == 0 ? b0 : (seg == 1 ? b1 : b2)) : b0;
    float bv[4];
#pragma unroll
    for (int n = 0; n < 4; ++n) {
        const int col = n0 + wn + n * 16 + fr;
        bv[n] = bias[(ACT == 3) ? (col - seg * 512) : col];
    }

#pragma unroll
    for (int m = 0; m < 4; ++m)
#pragma unroll
        for (int n = 0; n < 4; ++n)
#pragma unroll
            for (int j = 0; j < 4; ++j) {
                const int row = m0 + wm + m * 16 + (lane >> 4) * 4 + j;
                const int col = n0 + wn + n * 16 + fr;
                float v = acc[m][n][j] + bv[n];
                if (ACT == 2) v = geluf(v);
                else if (ACT == 3) { if (seg < 2) v = elu1f(v); }
                if (ACT == 3)
                    Cbf[(size_t)seg * SEGSTRIDE + (size_t)row * 512 + (col - seg * 512)] = f2b(v);
                else
                    Cbf[(size_t)row * N + col] = f2b(v);
            }
}

// ---------------------------------------------------------------------------
// bf16 MFMA GEMM (R8 config) for Wo / W2: 128x128, BK=64, 8 waves (2x4 ->
// 64x32), 2x32KB LDS -> 2 blocks/CU. RESID adds bf16 residual on kz==0;
// ATOMIC atomicAdds into U; WU plain-stores U.
// ---------------------------------------------------------------------------
template <int ACT, bool RESID, bool ATOMIC, bool WU, bool WBF16, int KSPLIT>
__global__ __launch_bounds__(512, 4) void gemm8(
    const unsigned short* __restrict__ A,
    const unsigned short* __restrict__ WT,
    const float* __restrict__ b0,
    const unsigned short* __restrict__ Xres,
    float* __restrict__ U, unsigned short* __restrict__ Cbf,
    int M, int N, int K)
{
    __shared__ short S[2][16384];

    const int t = threadIdx.x;
    const int m0 = blockIdx.x * 128, n0 = blockIdx.y * 128;
    const int kz = (KSPLIT > 1) ? blockIdx.z : 0;
    const int Kc = K / KSPLIT;
    const int kbeg = kz * Kc;
    const int lane = t & 63, wid = t >> 6;
    const int wm = (wid >> 2) * 64;
    const int wn = (wid & 3) * 32;
    const int fr = lane & 15, kg = lane >> 4;

    const unsigned short* gsrc[4];
    int ldso[4];
#pragma unroll
    for (int r = 0; r < 4; ++r) {
        const int u = (r & 1) ? (t + 512) : t;
        const bool isA = (r < 2);
        const int row = u >> 3, sp = u & 7, sl = sp ^ (row & 7);
        gsrc[r] = (isA ? A + (size_t)(m0 + row) * K
                       : WT + (size_t)(n0 + row) * K) + kbeg + sl * 8;
        ldso[r] = (isA ? 0 : 8192) + u * 8;
    }

    int aoff[2][4], boff[2][2];
#pragma unroll
    for (int h = 0; h < 2; ++h) {
#pragma unroll
        for (int m = 0; m < 4; ++m) {
            const int R = wm + m * 16 + fr;
            aoff[h][m] = R * 64 + (((h * 4 + kg) ^ (R & 7)) * 8);
        }
#pragma unroll
        for (int n = 0; n < 2; ++n) {
            const int R = wn + n * 16 + fr;
            boff[h][n] = 8192 + R * 64 + (((h * 4 + kg) ^ (R & 7)) * 8);
        }
    }

    f32x4 acc[4][2];
#pragma unroll
    for (int m = 0; m < 4; ++m)
#pragma unroll
        for (int n = 0; n < 2; ++n) acc[m][n] = (f32x4){0.f, 0.f, 0.f, 0.f};

#define STAGE(b, kt) do { _Pragma("unroll")                                  \
    for (int r = 0; r < 4; ++r)                                              \
        gload16(gsrc[r] + (size_t)(kt) * 64, &S[b][ldso[r]]); } while (0)

    const int NT = Kc >> 6;
    STAGE(0, 0);

    for (int td = 0; td < NT; ++td) {
        const int b = td & 1;
        if (td + 1 < NT) {
            STAGE(b ^ 1, td + 1);
            __builtin_amdgcn_sched_barrier(0);
            asm volatile("s_waitcnt vmcnt(4)");
        } else {
            __builtin_amdgcn_sched_barrier(0);
            asm volatile("s_waitcnt vmcnt(0)");
        }
        __builtin_amdgcn_sched_barrier(0);
        __builtin_amdgcn_s_barrier();
        __builtin_amdgcn_sched_barrier(0);

        short8v a0[4], b0f[2], a1[4], b1f[2];
#pragma unroll
        for (int m = 0; m < 4; ++m) a0[m] = *(const short8v*)&S[b][aoff[0][m]];
#pragma unroll
        for (int n = 0; n < 2; ++n) b0f[n] = *(const short8v*)&S[b][boff[0][n]];
#pragma unroll
        for (int m = 0; m < 4; ++m) a1[m] = *(const short8v*)&S[b][aoff[1][m]];
#pragma unroll
        for (int n = 0; n < 2; ++n) b1f[n] = *(const short8v*)&S[b][boff[1][n]];

        asm volatile("s_waitcnt lgkmcnt(6)");
        __builtin_amdgcn_sched_barrier(0);
        __builtin_amdgcn_s_setprio(1);
#pragma unroll
        for (int m = 0; m < 4; ++m)
#pragma unroll
            for (int n = 0; n < 2; ++n)
                acc[m][n] = __builtin_amdgcn_mfma_f32_16x16x32_bf16(
                    a0[m], b0f[n], acc[m][n], 0, 0, 0);
        __builtin_amdgcn_s_setprio(0);

        asm volatile("s_waitcnt lgkmcnt(0)");
        __builtin_amdgcn_sched_barrier(0);
        __builtin_amdgcn_s_setprio(1);
#pragma unroll
        for (int m = 0; m < 4; ++m)
#pragma unroll
            for (int n = 0; n < 2; ++n)
                acc[m][n] = __builtin_amdgcn_mfma_f32_16x16x32_bf16(
                    a1[m], b1f[n], acc[m][n], 0, 0, 0);
        __builtin_amdgcn_s_setprio(0);

        __builtin_amdgcn_sched_barrier(0);
        __builtin_amdgcn_s_barrier();
    }
#undef STAGE

    float bv[2];
#pragma unroll
    for (int n = 0; n < 2; ++n)
        bv[n] = b0[n0 + wn + n * 16 + fr];
    if (KSPLIT > 1 && kz != 0) { bv[0] = 0.f; bv[1] = 0.f; }

#pragma unroll
    for (int m = 0; m < 4; ++m)
#pragma unroll
        for (int n = 0; n < 2; ++n)
#pragma unroll
            for (int j = 0; j < 4; ++j) {
                const int row = m0 + wm + m * 16 + (lane >> 4) * 4 + j;
                const int col = n0 + wn + n * 16 + fr;
                float v = acc[m][n][j] + bv[n];
                if (RESID && kz == 0)
                    v += b2f(Xres[(size_t)row * 512 + col]);
                if (ACT == 1) v = elu1f(v);
                else if (ACT == 2) v = geluf(v);
                if (ATOMIC) {
                    atomicAdd(&U[(size_t)row * N + col], v);
                } else if (WU) {
                    U[(size_t)row * N + col] = v;
                }
                if (WBF16)
                    Cbf[(size_t)row * N + col] = f2b(v);
            }
}

// ---------------------------------------------------------------------------
// Weight transpose + bf16, batched over layers (blockIdx.z)
// ---------------------------------------------------------------------------
__global__ __launch_bounds__(256) void transpose_to_bf16(
    const float* __restrict__ W, unsigned short* __restrict__ WT, int K, int N,
    size_t wstride, size_t tstride)
{
    __shared__ float tile[32][33];
    const int l = blockIdx.z;
    W += (size_t)l * wstride;
    WT += (size_t)l * tstride;
    const int k0 = blockIdx.x * 32, n0 = blockIdx.y * 32;
    const int tx = threadIdx.x & 31, ty = threadIdx.x >> 5;
#pragma unroll
    for (int i = ty; i < 32; i += 8)
        tile[i][tx] = W[(size_t)(k0 + i) * N + n0 + tx];
    __syncthreads();
#pragma unroll
    for (int i = ty; i < 32; i += 8)
        WT[(size_t)(n0 + i) * K + k0 + tx] = f2b(tile[tx][i]);
}

// input convert: h f32 -> x_bf bf16 only
__global__ __launch_bounds__(256) void cvt_in(
    const float* __restrict__ h, unsigned short* __restrict__ xb, int n)
{
    const int i = (blockIdx.x * 256 + threadIdx.x) * 8;
    if (i >= n) return;
    f32x4 a = *(const f32x4*)(h + i);
    f32x4 b = *(const f32x4*)(h + i + 4);
    short8v p;
    p[0] = f2b(a[0]); p[1] = f2b(a[1]); p[2] = f2b(a[2]); p[3] = f2b(a[3]);
    p[4] = f2b(b[0]); p[5] = f2b(b[1]); p[6] = f2b(b[2]); p[7] = f2b(b[3]);
    *(short8v*)(xb + i) = p;
}

// swizzled 64x64 bf16 tile access: logical (row, sl) -> shorts offset
__device__ __forceinline__ int swzo(int row, int sl) {
    return row * 64 + ((sl ^ (row & 7)) << 3);
}

// ---------------------------------------------------------------------------
// Attention stage 1 (MFMA): per (b,h,chunk) KVt[e][d] = sum_j V[j][e]*K[j][d]
// ---------------------------------------------------------------------------
__global__ __launch_bounds__(256) void attn_stage1(
    const unsigned short* __restrict__ Kf, const unsigned short* __restrict__ Vf,
    unsigned short* __restrict__ KVp, float* __restrict__ zp)
{
    const int c = blockIdx.x, hh = blockIdx.y, bb = blockIdx.z;
    const int t = threadIdx.x;
    const int lane = t & 63, w = t >> 6;
    const int fr = lane & 15, g = lane >> 4;

    __shared__ unsigned short KTs[64 * 72];
    __shared__ unsigned short VTs[64 * 72];

    const size_t rowbase = (size_t)(bb * S_LEN + c * CHUNK);
    const int colbase = hh * DH;

    {
        const int r = lane, cs = w * 16;
        const unsigned short* kp = Kf + (rowbase + r) * DMODEL + colbase + cs;
        const unsigned short* vp = Vf + (rowbase + r) * DMODEL + colbase + cs;
        short8v k0 = *(const short8v*)kp, k1 = *(const short8v*)(kp + 8);
        short8v v0 = *(const short8v*)vp, v1 = *(const short8v*)(vp + 8);
#pragma unroll
        for (int i = 0; i < 8; ++i) {
            KTs[(cs + i) * 72 + r]     = (unsigned short)k0[i];
            KTs[(cs + 8 + i) * 72 + r] = (unsigned short)k1[i];
            VTs[(cs + i) * 72 + r]     = (unsigned short)v0[i];
            VTs[(cs + 8 + i) * 72 + r] = (unsigned short)v1[i];
        }
    }
    __syncthreads();

    f32x4 cacc[4];
#pragma unroll
    for (int nf = 0; nf < 4; ++nf) cacc[nf] = (f32x4){0.f, 0.f, 0.f, 0.f};

    const short8v a0 = *(const short8v*)&VTs[(w * 16 + fr) * 72 + g * 8];
    const short8v a1 = *(const short8v*)&VTs[(w * 16 + fr) * 72 + (4 + g) * 8];
#pragma unroll
    for (int nf = 0; nf < 4; ++nf) {
        short8v bq0 = *(const short8v*)&KTs[(nf * 16 + fr) * 72 + g * 8];
        short8v bq1 = *(const short8v*)&KTs[(nf * 16 + fr) * 72 + (4 + g) * 8];
        cacc[nf] = __builtin_amdgcn_mfma_f32_16x16x32_bf16(a0, bq0, cacc[nf], 0, 0, 0);
        cacc[nf] = __builtin_amdgcn_mfma_f32_16x16x32_bf16(a1, bq1, cacc[nf], 0, 0, 0);
    }

    const size_t base = ((size_t)(bb * NH + hh) * NCHUNK + c) * (DH * DH);
#pragma unroll
    for (int nf = 0; nf < 4; ++nf)
#pragma unroll
        for (int reg = 0; reg < 4; ++reg) {
            const int e = w * 16 + g * 4 + reg;
            const int d = nf * 16 + fr;
            KVp[base + e * 64 + d] = f2b(cacc[nf][reg]);
        }

    if (t < 64) {
        float s = 0.f;
#pragma unroll
        for (int sl = 0; sl < 8; ++sl) {
            short8v kv = *(const short8v*)&KTs[t * 72 + sl * 8];
#pragma unroll
            for (int i = 0; i < 8; ++i) s += b2f((unsigned short)kv[i]);
        }
        zp[((size_t)(bb * NH + hh) * NCHUNK + c) * DH + t] = s;
    }
}

// ---------------------------------------------------------------------------
// Attention stage 2: exclusive prefix over 32 chunk states per (b,h)
// ---------------------------------------------------------------------------
__global__ __launch_bounds__(256) void attn_stage2(
    const unsigned short* __restrict__ KVp, unsigned short* __restrict__ KVb,
    float* __restrict__ zp)
{
    const int bh = blockIdx.x;
    const int e = blockIdx.y * 256 + threadIdx.x;
    const size_t base = (size_t)bh * NCHUNK * (DH * DH) + e;
    float run = 0.f;
#pragma unroll 4
    for (int c = 0; c < NCHUNK; ++c) {
        const float tmp = b2f(KVp[base + (size_t)c * (DH * DH)]);
        KVb[base + (size_t)c * (DH * DH)] = f2b(run);
        run += tmp;
    }
    if (blockIdx.y == 0 && threadIdx.x < DH) {
        float rz = 0.f;
        const size_t zb = (size_t)bh * NCHUNK * DH + threadIdx.x;
#pragma unroll 4
        for (int c = 0; c < NCHUNK; ++c) {
            const float tmp = zp[zb + c * DH];
            zp[zb + c * DH] = rz;
            rz += tmp;
        }
    }
}

// ---------------------------------------------------------------------------
// Attention stage 3 (MFMA)
// ---------------------------------------------------------------------------
__global__ __launch_bounds__(256) void attn_stage3(
    const unsigned short* __restrict__ Qf, const unsigned short* __restrict__ Kf,
    const unsigned short* __restrict__ Vf, const unsigned short* __restrict__ KVb,
    const float* __restrict__ zp, unsigned short* __restrict__ Af)
{
    const int c = blockIdx.x, hh = blockIdx.y, bb = blockIdx.z;
    const int t = threadIdx.x;
    const int lane = t & 63, w = t >> 6;
    const int fr = lane & 15, g = lane >> 4;

    __shared__ unsigned short Qs[4096];
    __shared__ unsigned short Ks[4096];
    __shared__ unsigned short KVts[4096];
    __shared__ unsigned short VTs[64 * 72];
    __shared__ unsigned short Ps[64 * 72];
    __shared__ float zsh[DH];
    __shared__ float den_lds[64];

    const size_t rowbase = (size_t)(bb * S_LEN + c * CHUNK);
    const int colbase = hh * DH;
    const size_t kvbase = ((size_t)(bb * NH + hh) * NCHUNK + c) * (DH * DH);

#pragma unroll
    for (int iss = 0; iss < 2; ++iss) {
        const int u = iss * 256 + t, row = u >> 3, sl = u & 7;
        const int ssl = (sl ^ (row & 7)) * 8;
        gload16(Qf + (rowbase + row) * DMODEL + colbase + ssl, &Qs[(size_t)u * 8]);
        gload16(Kf + (rowbase + row) * DMODEL + colbase + ssl, &Ks[(size_t)u * 8]);
        gload16(KVb + kvbase + row * 64 + ssl, &KVts[(size_t)u * 8]);
    }
    {
        const int r = lane, cs = w * 16;
        const unsigned short* vp = Vf + (rowbase + r) * DMODEL + colbase + cs;
        short8v v0 = *(const short8v*)vp, v1 = *(const short8v*)(vp + 8);
#pragma unroll
        for (int i = 0; i < 8; ++i) {
            VTs[(cs + i) * 72 + r]     = (unsigned short)v0[i];
            VTs[(cs + 8 + i) * 72 + r] = (unsigned short)v1[i];
        }
    }
    if (t < DH) zsh[t] = zp[((size_t)(bb * NH + hh) * NCHUNK + c) * DH + t];
    __syncthreads();

    f32x4 c1[4];
#pragma unroll
    for (int mf = 0; mf < 4; ++mf) c1[mf] = (f32x4){0.f, 0.f, 0.f, 0.f};
    {
        const short8v bq0 = *(const short8v*)&Qs[swzo(w * 16 + fr, g)];
        const short8v bq1 = *(const short8v*)&Qs[swzo(w * 16 + fr, 4 + g)];
#pragma unroll
        for (int mf = 0; mf < 4; ++mf) {
            short8v ak0 = *(const short8v*)&Ks[swzo(mf * 16 + fr, g)];
            short8v ak1 = *(const short8v*)&Ks[swzo(mf * 16 + fr, 4 + g)];
            c1[mf] = __builtin_amdgcn_mfma_f32_16x16x32_bf16(ak0, bq0, c1[mf], 0, 0, 0);
            c1[mf] = __builtin_amdgcn_mfma_f32_16x16x32_bf16(ak1, bq1, c1[mf], 0, 0, 0);
        }
    }

    const int i_my = w * 16 + fr;
    float dint = 0.f;
#pragma unroll
    for (int mf = 0; mf < 4; ++mf)
#pragma unroll
        for (int reg = 0; reg < 4; ++reg) {
            const int j = mf * 16 + g * 4 + reg;
            const float v = (j <= i_my) ? c1[mf][reg] : 0.f;
            dint += v;
            Ps[i_my * 72 + j] = f2b(v);
        }
    dint += __shfl_xor(dint, 16);
    dint += __shfl_xor(dint, 32);

    float dpre = 0.f;
#pragma unroll
    for (int sl = 0; sl < 8; ++sl) {
        short8v qv = *(const short8v*)&Qs[swzo(i_my, sl)];
#pragma unroll
        for (int e = 0; e < 8; ++e) dpre += b2f((unsigned short)qv[e]) * zsh[sl * 8 + e];
    }
    if (g == 0) den_lds[i_my] = dpre + dint + ATT_EPS;

    f32x4 acc[4];
#pragma unroll
    for (int nf = 0; nf < 4; ++nf) acc[nf] = (f32x4){0.f, 0.f, 0.f, 0.f};
    {
        const short8v aq0 = *(const short8v*)&Qs[swzo(w * 16 + fr, g)];
        const short8v aq1 = *(const short8v*)&Qs[swzo(w * 16 + fr, 4 + g)];
#pragma unroll
        for (int nf = 0; nf < 4; ++nf) {
            short8v bkv0 = *(const short8v*)&KVts[swzo(nf * 16 + fr, g)];
            short8v bkv1 = *(const short8v*)&KVts[swzo(nf * 16 + fr, 4 + g)];
            acc[nf] = __builtin_amdgcn_mfma_f32_16x16x32_bf16(aq0, bkv0, acc[nf], 0, 0, 0);
            acc[nf] = __builtin_amdgcn_mfma_f32_16x16x32_bf16(aq1, bkv1, acc[nf], 0, 0, 0);
        }
        const short8v ap0 = *(const short8v*)&Ps[(w * 16 + fr) * 72 + g * 8];
        const short8v ap1 = *(const short8v*)&Ps[(w * 16 + fr) * 72 + (4 + g) * 8];
#pragma unroll
        for (int nf = 0; nf < 4; ++nf) {
            short8v bv0 = *(const short8v*)&VTs[(nf * 16 + fr) * 72 + g * 8];
            short8v bv1 = *(const short8v*)&VTs[(nf * 16 + fr) * 72 + (4 + g) * 8];
            acc[nf] = __builtin_amdgcn_mfma_f32_16x16x32_bf16(ap0, bv0, acc[nf], 0, 0, 0);
            acc[nf] = __builtin_amdgcn_mfma_f32_16x16x32_bf16(ap1, bv1, acc[nf], 0, 0, 0);
        }
    }

#pragma unroll
    for (int reg = 0; reg < 4; ++reg) {
        const int i = w * 16 + g * 4 + reg;
        const float inv = 1.f / den_lds[i];
        unsigned short* dst = Af + (rowbase + i) * DMODEL + colbase;
#pragma unroll
        for (int nf = 0; nf < 4; ++nf)
            dst[nf * 16 + fr] = f2b(acc[nf][reg] * inv);
    }
}

// ---------------------------------------------------------------------------
// LayerNorm: U (f32 pre-LN) -> x_bf (bf16). ZERO re-zeroes U after read.
// ---------------------------------------------------------------------------
__global__ __launch_bounds__(256) void ln_u2x(float* __restrict__ U,
                                              const float* __restrict__ g,
                                              const float* __restrict__ b,
                                              unsigned short* __restrict__ Xb,
                                              int ZERO)
{
    const size_t row = blockIdx.x * 4 + (threadIdx.x >> 6);
    const int t = threadIdx.x & 63;
    float* ur = U + row * DMODEL;
    f32x4 x0 = *(const f32x4*)&ur[t * 4];
    f32x4 x1 = *(const f32x4*)&ur[256 + t * 4];

    float s  = x0[0] + x0[1] + x0[2] + x0[3] + x1[0] + x1[1] + x1[2] + x1[3];
    float sq = x0[0]*x0[0] + x0[1]*x0[1] + x0[2]*x0[2] + x0[3]*x0[3] +
               x1[0]*x1[0] + x1[1]*x1[1] + x1[2]*x1[2] + x1[3]*x1[3];
#pragma unroll
    for (int m = 1; m < 64; m <<= 1) {
        s  += __shfl_xor(s, m);
        sq += __shfl_xor(sq, m);
    }
    const float mu  = s * (1.f / DMODEL);
    const float var = sq * (1.f / DMODEL) - mu * mu;
    const float rr  = rsqrtf(var + LN_EPS);

    const int c0 = t * 4, c1 = 256 + t * 4;
    f32x4 g0 = *(const f32x4*)&g[c0], g1v = *(const f32x4*)&g[c1];
    f32x4 b0 = *(const f32x4*)&b[c0], b1v = *(const f32x4*)&b[c1];
    unsigned short* xb = Xb + row * DMODEL;
    ushort4 u0, u1;
    u0.x = f2b((x0[0] - mu) * rr * g0[0] + b0[0]);
    u0.y = f2b((x0[1] - mu) * rr * g0[1] + b0[1]);
    u0.z = f2b((x0[2] - mu) * rr * g0[2] + b0[2]);
    u0.w = f2b((x0[3] - mu) * rr * g0[3] + b0[3]);
    u1.x = f2b((x1[0] - mu) * rr * g1v[0] + b1v[0]);
    u1.y = f2b((x1[1] - mu) * rr * g1v[1] + b1v[1]);
    u1.z = f2b((x1[2] - mu) * rr * g1v[2] + b1v[2]);
    u1.w = f2b((x1[3] - mu) * rr * g1v[3] + b1v[3]);
    *(ushort4*)&xb[c0] = u0;
    *(ushort4*)&xb[c1] = u1;
    if (ZERO) {
        *(f32x4*)&ur[c0] = (f32x4){0.f, 0.f, 0.f, 0.f};
        *(f32x4*)&ur[c1] = (f32x4){0.f, 0.f, 0.f, 0.f};
    }
}

// final LayerNorm: x_bf -> d_out (f32)
__global__ __launch_bounds__(256) void ln_final(const unsigned short* __restrict__ Xb,
                                                const float* __restrict__ g,
                                                const float* __restrict__ b,
                                                float* __restrict__ Out)
{
    const size_t row = blockIdx.x * 4 + (threadIdx.x >> 6);
    const int t = threadIdx.x & 63;
    const unsigned short* xr = Xb + row * DMODEL;
    short8v xv = *(const short8v*)&xr[t * 8];
    float x[8];
#pragma unroll
    for (int i = 0; i < 8; ++i) x[i] = b2f((unsigned short)xv[i]);

    float s = 0.f, sq = 0.f;
#pragma unroll
    for (int i = 0; i < 8; ++i) { s += x[i]; sq += x[i] * x[i]; }
#pragma unroll
    for (int m = 1; m < 64; m <<= 1) {
        s  += __shfl_xor(s, m);
        sq += __shfl_xor(sq, m);
    }
    const float mu  = s * (1.f / DMODEL);
    const float var = sq * (1.f / DMODEL) - mu * mu;
    const float rr  = rsqrtf(var + LN_EPS);

    float* orow = Out + row * DMODEL + t * 8;
    f32x4 o0, o1;
#pragma unroll
    for (int i = 0; i < 4; ++i) {
        o0[i] = (x[i] - mu) * rr * g[t * 8 + i] + b[t * 8 + i];
        o1[i] = (x[4 + i] - mu) * rr * g[t * 8 + 4 + i] + b[t * 8 + 4 + i];
    }
    *(f32x4*)orow = o0;
    *(f32x4*)(orow + 4) = o1;
}

// ---------------------------------------------------------------------------
extern "C" void kernel_launch(void* const* d_in, const int* in_sizes, int n_in,
                              void* d_out, int out_size, void* d_ws, size_t ws_size,
                              hipStream_t stream)
{
    const float* h   = (const float*)d_in[0];
    const float* Wq  = (const float*)d_in[1];
    const float* bq  = (const float*)d_in[2];
    const float* Wk  = (const float*)d_in[3];
    const float* bk  = (const float*)d_in[4];
    const float* Wv  = (const float*)d_in[5];
    const float* bv  = (const float*)d_in[6];
    const float* Wo  = (const float*)d_in[7];
    const float* bo  = (const float*)d_in[8];
    const float* W1  = (const float*)d_in[9];
    const float* b1  = (const float*)d_in[10];
    const float* W2  = (const float*)d_in[11];
    const float* b2  = (const float*)d_in[12];
    const float* g1  = (const float*)d_in[13];
    const float* be1 = (const float*)d_in[14];
    const float* g2  = (const float*)d_in[15];
    const float* be2 = (const float*)d_in[16];
    const float* gf  = (const float*)d_in[17];
    const float* bef = (const float*)d_in[18];

    char* ws = (char*)d_ws;
    const size_t MB = 1024 * 1024;
    unsigned short* x_bf = (unsigned short*)(ws);                 // 8 MB
    unsigned short* qkv  = (unsigned short*)(ws + 8 * MB);        // q|k|v 24 MB
    unsigned short* qb   = qkv;
    unsigned short* kb   = qkv + SEGSTRIDE;
    unsigned short* vb   = qkv + 2 * (size_t)SEGSTRIDE;
    unsigned short* ab   = (unsigned short*)(ws + 32 * MB);       // 8 MB
    unsigned short* hid  = (unsigned short*)(ws + 8 * MB);        // 32 MB alias q|k|v|a
    unsigned short* KVp  = (unsigned short*)(ws + 40 * MB);       // bf16 partials 8 MB
    unsigned short* KVb  = (unsigned short*)(ws + 48 * MB);       // prefix states 8 MB
    float* U             = (float*)(ws + 40 * MB);                // pre-LN f32 16 MB (aliases KVp/KVb)
    float* zp            = (float*)(ws + 56 * MB);                // 0.5 MB
    unsigned short* WTall = (unsigned short*)(ws + 57 * MB);      // 24 MB

    const int M = MROWS, D = DMODEL, DF = DFF;
    const size_t LSTR = 3 * 1024 * 1024;

    cvt_in<<<dim3(M * D / (256 * 8)), 256, 0, stream>>>(h, x_bf, M * D);
    // batched weight transposes (grid.z = layer)
    transpose_to_bf16<<<dim3(D / 32, D / 32, LAYERS), 256, 0, stream>>>(
        Wq, WTall, D, D, (size_t)D * D, LSTR);
    transpose_to_bf16<<<dim3(D / 32, D / 32, LAYERS), 256, 0, stream>>>(
        Wk, WTall + 262144, D, D, (size_t)D * D, LSTR);
    transpose_to_bf16<<<dim3(D / 32, D / 32, LAYERS), 256, 0, stream>>>(
        Wv, WTall + 524288, D, D, (size_t)D * D, LSTR);
    transpose_to_bf16<<<dim3(D / 32, D / 32, LAYERS), 256, 0, stream>>>(
        Wo, WTall + 786432, D, D, (size_t)D * D, LSTR);
    transpose_to_bf16<<<dim3(D / 32, DF / 32, LAYERS), 256, 0, stream>>>(
        W1, WTall + 1048576, D, DF, (size_t)D * DF, LSTR);
    transpose_to_bf16<<<dim3(DF / 32, D / 32, LAYERS), 256, 0, stream>>>(
        W2, WTall + 2097152, DF, D, (size_t)DF * D, LSTR);

    for (int l = 0; l < LAYERS; ++l) {
        unsigned short* WL = WTall + (size_t)l * LSTR;
        const unsigned short* WqkvT = WL;            // [1536][512]
        const unsigned short* WoT   = WL + 786432;   // [512][512]
        const unsigned short* W1T   = WL + 1048576;  // [2048][512]
        const unsigned short* W2T   = WL + 2097152;  // [512][2048]

        // fused q|k|v projection (elu+1 on q,k), bf16 out: 64x6 blocks, 3/CU
        gemmw<3><<<dim3(M / 128, 1536 / 256), 512, 0, stream>>>(
            x_bf, WqkvT, bq + (size_t)l * D, bk + (size_t)l * D, bv + (size_t)l * D,
            qkv, M, 1536, D);

        attn_stage1<<<dim3(NCHUNK, NH, NB), 256, 0, stream>>>(kb, vb, KVp, zp);
        attn_stage2<<<dim3(NB * NH, 16), 256, 0, stream>>>(KVp, KVb, zp);
        attn_stage3<<<dim3(NCHUNK, NH, NB), 256, 0, stream>>>(qb, kb, vb, KVb, zp, ab);

        // out projection + bf16 residual -> U (f32, plain store)
        gemm8<0, true, false, true, false, 1>
            <<<dim3(M / 128, D / 128), 512, 0, stream>>>(
            ab, WoT, bo + (size_t)l * D, x_bf, U, nullptr, M, D, D);
        // LN1: U -> x_bf ; zero U for W2's atomic accumulate
        ln_u2x<<<dim3(M / 4), 256, 0, stream>>>(U, g1 + (size_t)l * D, be1 + (size_t)l * D, x_bf, 1);

        // FFN: W1 wide-N (64x8 blocks, 3/CU) -> hid bf16
        gemmw<2><<<dim3(M / 128, DF / 256), 512, 0, stream>>>(
            x_bf, W1T, b1 + (size_t)l * DF, nullptr, nullptr, hid, M, DF, D);
        // W2 split-K=2, atomic into zeroed U, residual+bias on kz==0
        gemm8<0, true, true, false, false, 2>
            <<<dim3(M / 128, D / 128, 2), 512, 0, stream>>>(
            hid, W2T, b2 + (size_t)l * D, x_bf, U, nullptr, M, D, DF);
        // LN2: U -> x_bf
        ln_u2x<<<dim3(M / 4), 256, 0, stream>>>(U, g2 + (size_t)l * D, be2 + (size_t)l * D, x_bf, 0);
    }

    ln_final<<<dim3(M / 4), 256, 0, stream>>>(x_bf, gf, bef, (float*)d_out);
}

// Round 13
// 601.005 us; speedup vs baseline: 2.5500x; 2.5500x over previous
//
#include <hip/hip_runtime.h>
#include <hip/hip_bf16.h>
#include <math.h>

#define LAYERS 4
#define DMODEL 512
#define NH 8
#define DH 64
#define DFF 2048
#define NB 4
#define S_LEN 2048
#define MROWS 8192
#define CHUNK 64
#define NCHUNK 32            // S_LEN / CHUNK
#define ATT_EPS 1e-6f
#define LN_EPS 1e-5f
#define SEGSTRIDE (MROWS * DMODEL)   // 4194304 elems per q/k/v segment

typedef __attribute__((ext_vector_type(8))) short short8v;   // 8 bf16
typedef __attribute__((ext_vector_type(4))) float f32x4;

__device__ __forceinline__ float b2f(unsigned short u) {
    union { float f; unsigned u; } c; c.u = ((unsigned)u) << 16; return c.f;
}
__device__ __forceinline__ unsigned short f2b(float f) {
    union { float f; unsigned u; } c; c.f = f;
    unsigned r = c.u + 0x7FFFu + ((c.u >> 16) & 1u);
    return (unsigned short)(r >> 16);
}
__device__ __forceinline__ void gload16(const void* g, void* l) {
    __builtin_amdgcn_global_load_lds(
        (const __attribute__((address_space(1))) void*)g,
        (__attribute__((address_space(3))) void*)l, 16, 0, 0);
}
__device__ __forceinline__ float elu1f(float v) {
    return (v > 0.f) ? (v + 1.f) : __expf(v);
}
__device__ __forceinline__ float geluf(float v) {
    float u = 0.7978845608028654f * v * (1.f + 0.044715f * v * v);
    float th = 1.f - 2.f / (1.f + __expf(2.f * u));
    return 0.5f * v * (1.f + th);
}

// ---------------------------------------------------------------------------
// Wide-N bf16 MFMA GEMM for fat GEMMs (qkv, W1): BM=128, BN=256, BK=32,
// 8 waves (2Mx4N) each owning 64x64 -> 24 FLOP/LDS-byte (1.5x gemm8).
// __launch_bounds__(512,4): VGPR budget 128 (acc=64 + frags + addr fits, NO
// SPILL — R12's (512,6) capped at ~40 VGPR and spilled acc to scratch).
// 2x24KB LDS buffers; counted vmcnt(3); (row>>1)&3 both-sides swizzle.
// ---------------------------------------------------------------------------
template <int ACT>
__global__ __launch_bounds__(512, 4) void gemmw(
    const unsigned short* __restrict__ A,
    const unsigned short* __restrict__ WT,
    const float* __restrict__ b0, const float* __restrict__ b1,
    const float* __restrict__ b2,
    unsigned short* __restrict__ Cbf,
    int M, int N, int K)
{
    __shared__ short S[2][12288];   // [A 128x32 | B 256x32] swizzled, 24KB/buf

    const int t = threadIdx.x;
    const int m0 = blockIdx.x * 128, n0 = blockIdx.y * 256;
    const int lane = t & 63, wid = t >> 6;
    const int wm = (wid >> 2) * 64;   // 2 M-bands of 64
    const int wn = (wid & 3) * 64;    // 4 N-bands of 64
    const int fr = lane & 15, kg = lane >> 4;

    const unsigned short* gA;
    const unsigned short* gB0;
    const unsigned short* gB1;
    int loA, loB0, loB1;
    {
        const int rowA = t >> 2, spA = t & 3;
        gA = A + (size_t)(m0 + rowA) * K + (spA ^ ((rowA >> 1) & 3)) * 8;
        loA = t * 8;
        const int rB0 = t >> 2, sB0 = t & 3;
        gB0 = WT + (size_t)(n0 + rB0) * K + (sB0 ^ ((rB0 >> 1) & 3)) * 8;
        loB0 = 4096 + t * 8;
        const int u1 = t + 512;
        const int rB1 = u1 >> 2, sB1 = u1 & 3;
        gB1 = WT + (size_t)(n0 + rB1) * K + (sB1 ^ ((rB1 >> 1) & 3)) * 8;
        loB1 = 4096 + u1 * 8;
    }

    int aoff[4], boff[4];
#pragma unroll
    for (int m = 0; m < 4; ++m) {
        const int R = wm + m * 16 + fr;
        aoff[m] = R * 32 + ((kg ^ ((R >> 1) & 3)) << 3);
    }
#pragma unroll
    for (int n = 0; n < 4; ++n) {
        const int R = wn + n * 16 + fr;
        boff[n] = 4096 + R * 32 + ((kg ^ ((R >> 1) & 3)) << 3);
    }

    f32x4 acc[4][4];
#pragma unroll
    for (int m = 0; m < 4; ++m)
#pragma unroll
        for (int n = 0; n < 4; ++n) acc[m][n] = (f32x4){0.f, 0.f, 0.f, 0.f};

#define STAGE(b, kt) do {                                       \
    gload16(gA + (size_t)(kt) * 32, &S[b][loA]);                \
    gload16(gB0 + (size_t)(kt) * 32, &S[b][loB0]);              \
    gload16(gB1 + (size_t)(kt) * 32, &S[b][loB1]); } while (0)

    const int NT = K >> 5;
    STAGE(0, 0);

    for (int td = 0; td < NT; ++td) {
        const int b = td & 1;
        if (td + 1 < NT) {
            STAGE(b ^ 1, td + 1);
            __builtin_amdgcn_sched_barrier(0);
            asm volatile("s_waitcnt vmcnt(3)");   // tile td landed
        } else {
            __builtin_amdgcn_sched_barrier(0);
            asm volatile("s_waitcnt vmcnt(0)");
        }
        __builtin_amdgcn_sched_barrier(0);
        __builtin_amdgcn_s_barrier();
        __builtin_amdgcn_sched_barrier(0);

        short8v af[4], bf[4];
#pragma unroll
        for (int m = 0; m < 4; ++m) af[m] = *(const short8v*)&S[b][aoff[m]];
#pragma unroll
        for (int n = 0; n < 4; ++n) bf[n] = *(const short8v*)&S[b][boff[n]];

        asm volatile("s_waitcnt lgkmcnt(0)");
        __builtin_amdgcn_sched_barrier(0);
        __builtin_amdgcn_s_setprio(1);
#pragma unroll
        for (int m = 0; m < 4; ++m)
#pragma unroll
            for (int n = 0; n < 4; ++n)
                acc[m][n] = __builtin_amdgcn_mfma_f32_16x16x32_bf16(
                    af[m], bf[n], acc[m][n], 0, 0, 0);
        __builtin_amdgcn_s_setprio(0);

        __builtin_amdgcn_sched_barrier(0);
        __builtin_amdgcn_s_barrier();   // protect buf b before restage
    }
#undef STAGE

    // epilogue (BN=256 tile never straddles a 512-col segment)
    const int seg = (ACT == 3) ? (n0 >> 9) : 0;
    const float* bias = (ACT == 3) ? (seg == 0 ? b0 : (seg == 1 ? b1 : b2)) : b0;
    float bv[4];
#pragma unroll
    for (int n = 0; n < 4; ++n) {
        const int col = n0 + wn + n * 16 + fr;
        bv[n] = bias[(ACT == 3) ? (col - seg * 512) : col];
    }

#pragma unroll
    for (int m = 0; m < 4; ++m)
#pragma unroll
        for (int n = 0; n < 4; ++n)
#pragma unroll
            for (int j = 0; j < 4; ++j) {
                const int row = m0 + wm + m * 16 + (lane >> 4) * 4 + j;
                const int col = n0 + wn + n * 16 + fr;
                float v = acc[m][n][j] + bv[n];
                if (ACT == 2) v = geluf(v);
                else if (ACT == 3) { if (seg < 2) v = elu1f(v); }
                if (ACT == 3)
                    Cbf[(size_t)seg * SEGSTRIDE + (size_t)row * 512 + (col - seg * 512)] = f2b(v);
                else
                    Cbf[(size_t)row * N + col] = f2b(v);
            }
}

// ---------------------------------------------------------------------------
// bf16 MFMA GEMM (R8/R11 proven config) for Wo / W2: 128x128, BK=64, 8 waves
// (2x4 -> 64x32), 2x32KB LDS -> 2 blocks/CU. RESID adds bf16 residual on
// kz==0; ATOMIC atomicAdds into U; WU plain-stores U.
// ---------------------------------------------------------------------------
template <int ACT, bool RESID, bool ATOMIC, bool WU, bool WBF16, int KSPLIT>
__global__ __launch_bounds__(512, 4) void gemm8(
    const unsigned short* __restrict__ A,
    const unsigned short* __restrict__ WT,
    const float* __restrict__ b0,
    const unsigned short* __restrict__ Xres,
    float* __restrict__ U, unsigned short* __restrict__ Cbf,
    int M, int N, int K)
{
    __shared__ short S[2][16384];

    const int t = threadIdx.x;
    const int m0 = blockIdx.x * 128, n0 = blockIdx.y * 128;
    const int kz = (KSPLIT > 1) ? blockIdx.z : 0;
    const int Kc = K / KSPLIT;
    const int kbeg = kz * Kc;
    const int lane = t & 63, wid = t >> 6;
    const int wm = (wid >> 2) * 64;
    const int wn = (wid & 3) * 32;
    const int fr = lane & 15, kg = lane >> 4;

    const unsigned short* gsrc[4];
    int ldso[4];
#pragma unroll
    for (int r = 0; r < 4; ++r) {
        const int u = (r & 1) ? (t + 512) : t;
        const bool isA = (r < 2);
        const int row = u >> 3, sp = u & 7, sl = sp ^ (row & 7);
        gsrc[r] = (isA ? A + (size_t)(m0 + row) * K
                       : WT + (size_t)(n0 + row) * K) + kbeg + sl * 8;
        ldso[r] = (isA ? 0 : 8192) + u * 8;
    }

    int aoff[2][4], boff[2][2];
#pragma unroll
    for (int h = 0; h < 2; ++h) {
#pragma unroll
        for (int m = 0; m < 4; ++m) {
            const int R = wm + m * 16 + fr;
            aoff[h][m] = R * 64 + (((h * 4 + kg) ^ (R & 7)) * 8);
        }
#pragma unroll
        for (int n = 0; n < 2; ++n) {
            const int R = wn + n * 16 + fr;
            boff[h][n] = 8192 + R * 64 + (((h * 4 + kg) ^ (R & 7)) * 8);
        }
    }

    f32x4 acc[4][2];
#pragma unroll
    for (int m = 0; m < 4; ++m)
#pragma unroll
        for (int n = 0; n < 2; ++n) acc[m][n] = (f32x4){0.f, 0.f, 0.f, 0.f};

#define STAGE(b, kt) do { _Pragma("unroll")                                  \
    for (int r = 0; r < 4; ++r)                                              \
        gload16(gsrc[r] + (size_t)(kt) * 64, &S[b][ldso[r]]); } while (0)

    const int NT = Kc >> 6;
    STAGE(0, 0);

    for (int td = 0; td < NT; ++td) {
        const int b = td & 1;
        if (td + 1 < NT) {
            STAGE(b ^ 1, td + 1);
            __builtin_amdgcn_sched_barrier(0);
            asm volatile("s_waitcnt vmcnt(4)");
        } else {
            __builtin_amdgcn_sched_barrier(0);
            asm volatile("s_waitcnt vmcnt(0)");
        }
        __builtin_amdgcn_sched_barrier(0);
        __builtin_amdgcn_s_barrier();
        __builtin_amdgcn_sched_barrier(0);

        short8v a0[4], b0f[2], a1[4], b1f[2];
#pragma unroll
        for (int m = 0; m < 4; ++m) a0[m] = *(const short8v*)&S[b][aoff[0][m]];
#pragma unroll
        for (int n = 0; n < 2; ++n) b0f[n] = *(const short8v*)&S[b][boff[0][n]];
#pragma unroll
        for (int m = 0; m < 4; ++m) a1[m] = *(const short8v*)&S[b][aoff[1][m]];
#pragma unroll
        for (int n = 0; n < 2; ++n) b1f[n] = *(const short8v*)&S[b][boff[1][n]];

        asm volatile("s_waitcnt lgkmcnt(6)");
        __builtin_amdgcn_sched_barrier(0);
        __builtin_amdgcn_s_setprio(1);
#pragma unroll
        for (int m = 0; m < 4; ++m)
#pragma unroll
            for (int n = 0; n < 2; ++n)
                acc[m][n] = __builtin_amdgcn_mfma_f32_16x16x32_bf16(
                    a0[m], b0f[n], acc[m][n], 0, 0, 0);
        __builtin_amdgcn_s_setprio(0);

        asm volatile("s_waitcnt lgkmcnt(0)");
        __builtin_amdgcn_sched_barrier(0);
        __builtin_amdgcn_s_setprio(1);
#pragma unroll
        for (int m = 0; m < 4; ++m)
#pragma unroll
            for (int n = 0; n < 2; ++n)
                acc[m][n] = __builtin_amdgcn_mfma_f32_16x16x32_bf16(
                    a1[m], b1f[n], acc[m][n], 0, 0, 0);
        __builtin_amdgcn_s_setprio(0);

        __builtin_amdgcn_sched_barrier(0);
        __builtin_amdgcn_s_barrier();
    }
#undef STAGE

    float bv[2];
#pragma unroll
    for (int n = 0; n < 2; ++n)
        bv[n] = b0[n0 + wn + n * 16 + fr];
    if (KSPLIT > 1 && kz != 0) { bv[0] = 0.f; bv[1] = 0.f; }

#pragma unroll
    for (int m = 0; m < 4; ++m)
#pragma unroll
        for (int n = 0; n < 2; ++n)
#pragma unroll
            for (int j = 0; j < 4; ++j) {
                const int row = m0 + wm + m * 16 + (lane >> 4) * 4 + j;
                const int col = n0 + wn + n * 16 + fr;
                float v = acc[m][n][j] + bv[n];
                if (RESID && kz == 0)
                    v += b2f(Xres[(size_t)row * 512 + col]);
                if (ACT == 1) v = elu1f(v);
                else if (ACT == 2) v = geluf(v);
                if (ATOMIC) {
                    atomicAdd(&U[(size_t)row * N + col], v);
                } else if (WU) {
                    U[(size_t)row * N + col] = v;
                }
                if (WBF16)
                    Cbf[(size_t)row * N + col] = f2b(v);
            }
}

// ---------------------------------------------------------------------------
// Weight transpose + bf16, batched over layers (blockIdx.z)
// ---------------------------------------------------------------------------
__global__ __launch_bounds__(256) void transpose_to_bf16(
    const float* __restrict__ W, unsigned short* __restrict__ WT, int K, int N,
    size_t wstride, size_t tstride)
{
    __shared__ float tile[32][33];
    const int l = blockIdx.z;
    W += (size_t)l * wstride;
    WT += (size_t)l * tstride;
    const int k0 = blockIdx.x * 32, n0 = blockIdx.y * 32;
    const int tx = threadIdx.x & 31, ty = threadIdx.x >> 5;
#pragma unroll
    for (int i = ty; i < 32; i += 8)
        tile[i][tx] = W[(size_t)(k0 + i) * N + n0 + tx];
    __syncthreads();
#pragma unroll
    for (int i = ty; i < 32; i += 8)
        WT[(size_t)(n0 + i) * K + k0 + tx] = f2b(tile[tx][i]);
}

// input convert: h f32 -> x_bf bf16 only
__global__ __launch_bounds__(256) void cvt_in(
    const float* __restrict__ h, unsigned short* __restrict__ xb, int n)
{
    const int i = (blockIdx.x * 256 + threadIdx.x) * 8;
    if (i >= n) return;
    f32x4 a = *(const f32x4*)(h + i);
    f32x4 b = *(const f32x4*)(h + i + 4);
    short8v p;
    p[0] = f2b(a[0]); p[1] = f2b(a[1]); p[2] = f2b(a[2]); p[3] = f2b(a[3]);
    p[4] = f2b(b[0]); p[5] = f2b(b[1]); p[6] = f2b(b[2]); p[7] = f2b(b[3]);
    *(short8v*)(xb + i) = p;
}

// swizzled 64x64 bf16 tile access: logical (row, sl) -> shorts offset
__device__ __forceinline__ int swzo(int row, int sl) {
    return row * 64 + ((sl ^ (row & 7)) << 3);
}

// ---------------------------------------------------------------------------
// Attention stage 1 (MFMA): per (b,h,chunk) KVt[e][d] = sum_j V[j][e]*K[j][d]
// ---------------------------------------------------------------------------
__global__ __launch_bounds__(256) void attn_stage1(
    const unsigned short* __restrict__ Kf, const unsigned short* __restrict__ Vf,
    unsigned short* __restrict__ KVp, float* __restrict__ zp)
{
    const int c = blockIdx.x, hh = blockIdx.y, bb = blockIdx.z;
    const int t = threadIdx.x;
    const int lane = t & 63, w = t >> 6;
    const int fr = lane & 15, g = lane >> 4;

    __shared__ unsigned short KTs[64 * 72];
    __shared__ unsigned short VTs[64 * 72];

    const size_t rowbase = (size_t)(bb * S_LEN + c * CHUNK);
    const int colbase = hh * DH;

    {
        const int r = lane, cs = w * 16;
        const unsigned short* kp = Kf + (rowbase + r) * DMODEL + colbase + cs;
        const unsigned short* vp = Vf + (rowbase + r) * DMODEL + colbase + cs;
        short8v k0 = *(const short8v*)kp, k1 = *(const short8v*)(kp + 8);
        short8v v0 = *(const short8v*)vp, v1 = *(const short8v*)(vp + 8);
#pragma unroll
        for (int i = 0; i < 8; ++i) {
            KTs[(cs + i) * 72 + r]     = (unsigned short)k0[i];
            KTs[(cs + 8 + i) * 72 + r] = (unsigned short)k1[i];
            VTs[(cs + i) * 72 + r]     = (unsigned short)v0[i];
            VTs[(cs + 8 + i) * 72 + r] = (unsigned short)v1[i];
        }
    }
    __syncthreads();

    f32x4 cacc[4];
#pragma unroll
    for (int nf = 0; nf < 4; ++nf) cacc[nf] = (f32x4){0.f, 0.f, 0.f, 0.f};

    const short8v a0 = *(const short8v*)&VTs[(w * 16 + fr) * 72 + g * 8];
    const short8v a1 = *(const short8v*)&VTs[(w * 16 + fr) * 72 + (4 + g) * 8];
#pragma unroll
    for (int nf = 0; nf < 4; ++nf) {
        short8v bq0 = *(const short8v*)&KTs[(nf * 16 + fr) * 72 + g * 8];
        short8v bq1 = *(const short8v*)&KTs[(nf * 16 + fr) * 72 + (4 + g) * 8];
        cacc[nf] = __builtin_amdgcn_mfma_f32_16x16x32_bf16(a0, bq0, cacc[nf], 0, 0, 0);
        cacc[nf] = __builtin_amdgcn_mfma_f32_16x16x32_bf16(a1, bq1, cacc[nf], 0, 0, 0);
    }

    const size_t base = ((size_t)(bb * NH + hh) * NCHUNK + c) * (DH * DH);
#pragma unroll
    for (int nf = 0; nf < 4; ++nf)
#pragma unroll
        for (int reg = 0; reg < 4; ++reg) {
            const int e = w * 16 + g * 4 + reg;
            const int d = nf * 16 + fr;
            KVp[base + e * 64 + d] = f2b(cacc[nf][reg]);
        }

    if (t < 64) {
        float s = 0.f;
#pragma unroll
        for (int sl = 0; sl < 8; ++sl) {
            short8v kv = *(const short8v*)&KTs[t * 72 + sl * 8];
#pragma unroll
            for (int i = 0; i < 8; ++i) s += b2f((unsigned short)kv[i]);
        }
        zp[((size_t)(bb * NH + hh) * NCHUNK + c) * DH + t] = s;
    }
}

// ---------------------------------------------------------------------------
// Attention stage 2: exclusive prefix over 32 chunk states per (b,h)
// ---------------------------------------------------------------------------
__global__ __launch_bounds__(256) void attn_stage2(
    const unsigned short* __restrict__ KVp, unsigned short* __restrict__ KVb,
    float* __restrict__ zp)
{
    const int bh = blockIdx.x;
    const int e = blockIdx.y * 256 + threadIdx.x;
    const size_t base = (size_t)bh * NCHUNK * (DH * DH) + e;
    float run = 0.f;
#pragma unroll 4
    for (int c = 0; c < NCHUNK; ++c) {
        const float tmp = b2f(KVp[base + (size_t)c * (DH * DH)]);
        KVb[base + (size_t)c * (DH * DH)] = f2b(run);
        run += tmp;
    }
    if (blockIdx.y == 0 && threadIdx.x < DH) {
        float rz = 0.f;
        const size_t zb = (size_t)bh * NCHUNK * DH + threadIdx.x;
#pragma unroll 4
        for (int c = 0; c < NCHUNK; ++c) {
            const float tmp = zp[zb + c * DH];
            zp[zb + c * DH] = rz;
            rz += tmp;
        }
    }
}

// ---------------------------------------------------------------------------
// Attention stage 3 (MFMA)
// ---------------------------------------------------------------------------
__global__ __launch_bounds__(256) void attn_stage3(
    const unsigned short* __restrict__ Qf, const unsigned short* __restrict__ Kf,
    const unsigned short* __restrict__ Vf, const unsigned short* __restrict__ KVb,
    const float* __restrict__ zp, unsigned short* __restrict__ Af)
{
    const int c = blockIdx.x, hh = blockIdx.y, bb = blockIdx.z;
    const int t = threadIdx.x;
    const int lane = t & 63, w = t >> 6;
    const int fr = lane & 15, g = lane >> 4;

    __shared__ unsigned short Qs[4096];
    __shared__ unsigned short Ks[4096];
    __shared__ unsigned short KVts[4096];
    __shared__ unsigned short VTs[64 * 72];
    __shared__ unsigned short Ps[64 * 72];
    __shared__ float zsh[DH];
    __shared__ float den_lds[64];

    const size_t rowbase = (size_t)(bb * S_LEN + c * CHUNK);
    const int colbase = hh * DH;
    const size_t kvbase = ((size_t)(bb * NH + hh) * NCHUNK + c) * (DH * DH);

#pragma unroll
    for (int iss = 0; iss < 2; ++iss) {
        const int u = iss * 256 + t, row = u >> 3, sl = u & 7;
        const int ssl = (sl ^ (row & 7)) * 8;
        gload16(Qf + (rowbase + row) * DMODEL + colbase + ssl, &Qs[(size_t)u * 8]);
        gload16(Kf + (rowbase + row) * DMODEL + colbase + ssl, &Ks[(size_t)u * 8]);
        gload16(KVb + kvbase + row * 64 + ssl, &KVts[(size_t)u * 8]);
    }
    {
        const int r = lane, cs = w * 16;
        const unsigned short* vp = Vf + (rowbase + r) * DMODEL + colbase + cs;
        short8v v0 = *(const short8v*)vp, v1 = *(const short8v*)(vp + 8);
#pragma unroll
        for (int i = 0; i < 8; ++i) {
            VTs[(cs + i) * 72 + r]     = (unsigned short)v0[i];
            VTs[(cs + 8 + i) * 72 + r] = (unsigned short)v1[i];
        }
    }
    if (t < DH) zsh[t] = zp[((size_t)(bb * NH + hh) * NCHUNK + c) * DH + t];
    __syncthreads();

    f32x4 c1[4];
#pragma unroll
    for (int mf = 0; mf < 4; ++mf) c1[mf] = (f32x4){0.f, 0.f, 0.f, 0.f};
    {
        const short8v bq0 = *(const short8v*)&Qs[swzo(w * 16 + fr, g)];
        const short8v bq1 = *(const short8v*)&Qs[swzo(w * 16 + fr, 4 + g)];
#pragma unroll
        for (int mf = 0; mf < 4; ++mf) {
            short8v ak0 = *(const short8v*)&Ks[swzo(mf * 16 + fr, g)];
            short8v ak1 = *(const short8v*)&Ks[swzo(mf * 16 + fr, 4 + g)];
            c1[mf] = __builtin_amdgcn_mfma_f32_16x16x32_bf16(ak0, bq0, c1[mf], 0, 0, 0);
            c1[mf] = __builtin_amdgcn_mfma_f32_16x16x32_bf16(ak1, bq1, c1[mf], 0, 0, 0);
        }
    }

    const int i_my = w * 16 + fr;
    float dint = 0.f;
#pragma unroll
    for (int mf = 0; mf < 4; ++mf)
#pragma unroll
        for (int reg = 0; reg < 4; ++reg) {
            const int j = mf * 16 + g * 4 + reg;
            const float v = (j <= i_my) ? c1[mf][reg] : 0.f;
            dint += v;
            Ps[i_my * 72 + j] = f2b(v);
        }
    dint += __shfl_xor(dint, 16);
    dint += __shfl_xor(dint, 32);

    float dpre = 0.f;
#pragma unroll
    for (int sl = 0; sl < 8; ++sl) {
        short8v qv = *(const short8v*)&Qs[swzo(i_my, sl)];
#pragma unroll
        for (int e = 0; e < 8; ++e) dpre += b2f((unsigned short)qv[e]) * zsh[sl * 8 + e];
    }
    if (g == 0) den_lds[i_my] = dpre + dint + ATT_EPS;

    f32x4 acc[4];
#pragma unroll
    for (int nf = 0; nf < 4; ++nf) acc[nf] = (f32x4){0.f, 0.f, 0.f, 0.f};
    {
        const short8v aq0 = *(const short8v*)&Qs[swzo(w * 16 + fr, g)];
        const short8v aq1 = *(const short8v*)&Qs[swzo(w * 16 + fr, 4 + g)];
#pragma unroll
        for (int nf = 0; nf < 4; ++nf) {
            short8v bkv0 = *(const short8v*)&KVts[swzo(nf * 16 + fr, g)];
            short8v bkv1 = *(const short8v*)&KVts[swzo(nf * 16 + fr, 4 + g)];
            acc[nf] = __builtin_amdgcn_mfma_f32_16x16x32_bf16(aq0, bkv0, acc[nf], 0, 0, 0);
            acc[nf] = __builtin_amdgcn_mfma_f32_16x16x32_bf16(aq1, bkv1, acc[nf], 0, 0, 0);
        }
        const short8v ap0 = *(const short8v*)&Ps[(w * 16 + fr) * 72 + g * 8];
        const short8v ap1 = *(const short8v*)&Ps[(w * 16 + fr) * 72 + (4 + g) * 8];
#pragma unroll
        for (int nf = 0; nf < 4; ++nf) {
            short8v bv0 = *(const short8v*)&VTs[(nf * 16 + fr) * 72 + g * 8];
            short8v bv1 = *(const short8v*)&VTs[(nf * 16 + fr) * 72 + (4 + g) * 8];
            acc[nf] = __builtin_amdgcn_mfma_f32_16x16x32_bf16(ap0, bv0, acc[nf], 0, 0, 0);
            acc[nf] = __builtin_amdgcn_mfma_f32_16x16x32_bf16(ap1, bv1, acc[nf], 0, 0, 0);
        }
    }

#pragma unroll
    for (int reg = 0; reg < 4; ++reg) {
        const int i = w * 16 + g * 4 + reg;
        const float inv = 1.f / den_lds[i];
        unsigned short* dst = Af + (rowbase + i) * DMODEL + colbase;
#pragma unroll
        for (int nf = 0; nf < 4; ++nf)
            dst[nf * 16 + fr] = f2b(acc[nf][reg] * inv);
    }
}

// ---------------------------------------------------------------------------
// LayerNorm: U (f32 pre-LN) -> x_bf (bf16). ZERO re-zeroes U after read.
// ---------------------------------------------------------------------------
__global__ __launch_bounds__(256) void ln_u2x(float* __restrict__ U,
                                              const float* __restrict__ g,
                                              const float* __restrict__ b,
                                              unsigned short* __restrict__ Xb,
                                              int ZERO)
{
    const size_t row = blockIdx.x * 4 + (threadIdx.x >> 6);
    const int t = threadIdx.x & 63;
    float* ur = U + row * DMODEL;
    f32x4 x0 = *(const f32x4*)&ur[t * 4];
    f32x4 x1 = *(const f32x4*)&ur[256 + t * 4];

    float s  = x0[0] + x0[1] + x0[2] + x0[3] + x1[0] + x1[1] + x1[2] + x1[3];
    float sq = x0[0]*x0[0] + x0[1]*x0[1] + x0[2]*x0[2] + x0[3]*x0[3] +
               x1[0]*x1[0] + x1[1]*x1[1] + x1[2]*x1[2] + x1[3]*x1[3];
#pragma unroll
    for (int m = 1; m < 64; m <<= 1) {
        s  += __shfl_xor(s, m);
        sq += __shfl_xor(sq, m);
    }
    const float mu  = s * (1.f / DMODEL);
    const float var = sq * (1.f / DMODEL) - mu * mu;
    const float rr  = rsqrtf(var + LN_EPS);

    const int c0 = t * 4, c1 = 256 + t * 4;
    f32x4 g0 = *(const f32x4*)&g[c0], g1v = *(const f32x4*)&g[c1];
    f32x4 b0 = *(const f32x4*)&b[c0], b1v = *(const f32x4*)&b[c1];
    unsigned short* xb = Xb + row * DMODEL;
    ushort4 u0, u1;
    u0.x = f2b((x0[0] - mu) * rr * g0[0] + b0[0]);
    u0.y = f2b((x0[1] - mu) * rr * g0[1] + b0[1]);
    u0.z = f2b((x0[2] - mu) * rr * g0[2] + b0[2]);
    u0.w = f2b((x0[3] - mu) * rr * g0[3] + b0[3]);
    u1.x = f2b((x1[0] - mu) * rr * g1v[0] + b1v[0]);
    u1.y = f2b((x1[1] - mu) * rr * g1v[1] + b1v[1]);
    u1.z = f2b((x1[2] - mu) * rr * g1v[2] + b1v[2]);
    u1.w = f2b((x1[3] - mu) * rr * g1v[3] + b1v[3]);
    *(ushort4*)&xb[c0] = u0;
    *(ushort4*)&xb[c1] = u1;
    if (ZERO) {
        *(f32x4*)&ur[c0] = (f32x4){0.f, 0.f, 0.f, 0.f};
        *(f32x4*)&ur[c1] = (f32x4){0.f, 0.f, 0.f, 0.f};
    }
}

// final LayerNorm: x_bf -> d_out (f32)
__global__ __launch_bounds__(256) void ln_final(const unsigned short* __restrict__ Xb,
                                                const float* __restrict__ g,
                                                const float* __restrict__ b,
                                                float* __restrict__ Out)
{
    const size_t row = blockIdx.x * 4 + (threadIdx.x >> 6);
    const int t = threadIdx.x & 63;
    const unsigned short* xr = Xb + row * DMODEL;
    short8v xv = *(const short8v*)&xr[t * 8];
    float x[8];
#pragma unroll
    for (int i = 0; i < 8; ++i) x[i] = b2f((unsigned short)xv[i]);

    float s = 0.f, sq = 0.f;
#pragma unroll
    for (int i = 0; i < 8; ++i) { s += x[i]; sq += x[i] * x[i]; }
#pragma unroll
    for (int m = 1; m < 64; m <<= 1) {
        s  += __shfl_xor(s, m);
        sq += __shfl_xor(sq, m);
    }
    const float mu  = s * (1.f / DMODEL);
    const float var = sq * (1.f / DMODEL) - mu * mu;
    const float rr  = rsqrtf(var + LN_EPS);

    float* orow = Out + row * DMODEL + t * 8;
    f32x4 o0, o1;
#pragma unroll
    for (int i = 0; i < 4; ++i) {
        o0[i] = (x[i] - mu) * rr * g[t * 8 + i] + b[t * 8 + i];
        o1[i] = (x[4 + i] - mu) * rr * g[t * 8 + 4 + i] + b[t * 8 + 4 + i];
    }
    *(f32x4*)orow = o0;
    *(f32x4*)(orow + 4) = o1;
}

// ---------------------------------------------------------------------------
extern "C" void kernel_launch(void* const* d_in, const int* in_sizes, int n_in,
                              void* d_out, int out_size, void* d_ws, size_t ws_size,
                              hipStream_t stream)
{
    const float* h   = (const float*)d_in[0];
    const float* Wq  = (const float*)d_in[1];
    const float* bq  = (const float*)d_in[2];
    const float* Wk  = (const float*)d_in[3];
    const float* bk  = (const float*)d_in[4];
    const float* Wv  = (const float*)d_in[5];
    const float* bv  = (const float*)d_in[6];
    const float* Wo  = (const float*)d_in[7];
    const float* bo  = (const float*)d_in[8];
    const float* W1  = (const float*)d_in[9];
    const float* b1  = (const float*)d_in[10];
    const float* W2  = (const float*)d_in[11];
    const float* b2  = (const float*)d_in[12];
    const float* g1  = (const float*)d_in[13];
    const float* be1 = (const float*)d_in[14];
    const float* g2  = (const float*)d_in[15];
    const float* be2 = (const float*)d_in[16];
    const float* gf  = (const float*)d_in[17];
    const float* bef = (const float*)d_in[18];

    char* ws = (char*)d_ws;
    const size_t MB = 1024 * 1024;
    unsigned short* x_bf = (unsigned short*)(ws);                 // 8 MB
    unsigned short* qkv  = (unsigned short*)(ws + 8 * MB);        // q|k|v 24 MB
    unsigned short* qb   = qkv;
    unsigned short* kb   = qkv + SEGSTRIDE;
    unsigned short* vb   = qkv + 2 * (size_t)SEGSTRIDE;
    unsigned short* ab   = (unsigned short*)(ws + 32 * MB);       // 8 MB
    unsigned short* hid  = (unsigned short*)(ws + 8 * MB);        // 32 MB alias q|k|v|a
    unsigned short* KVp  = (unsigned short*)(ws + 40 * MB);       // bf16 partials 8 MB
    unsigned short* KVb  = (unsigned short*)(ws + 48 * MB);       // prefix states 8 MB
    float* U             = (float*)(ws + 40 * MB);                // pre-LN f32 16 MB (aliases KVp/KVb)
    float* zp            = (float*)(ws + 56 * MB);                // 0.5 MB
    unsigned short* WTall = (unsigned short*)(ws + 57 * MB);      // 24 MB

    const int M = MROWS, D = DMODEL, DF = DFF;
    const size_t LSTR = 3 * 1024 * 1024;

    cvt_in<<<dim3(M * D / (256 * 8)), 256, 0, stream>>>(h, x_bf, M * D);
    transpose_to_bf16<<<dim3(D / 32, D / 32, LAYERS), 256, 0, stream>>>(
        Wq, WTall, D, D, (size_t)D * D, LSTR);
    transpose_to_bf16<<<dim3(D / 32, D / 32, LAYERS), 256, 0, stream>>>(
        Wk, WTall + 262144, D, D, (size_t)D * D, LSTR);
    transpose_to_bf16<<<dim3(D / 32, D / 32, LAYERS), 256, 0, stream>>>(
        Wv, WTall + 524288, D, D, (size_t)D * D, LSTR);
    transpose_to_bf16<<<dim3(D / 32, D / 32, LAYERS), 256, 0, stream>>>(
        Wo, WTall + 786432, D, D, (size_t)D * D, LSTR);
    transpose_to_bf16<<<dim3(D / 32, DF / 32, LAYERS), 256, 0, stream>>>(
        W1, WTall + 1048576, D, DF, (size_t)D * DF, LSTR);
    transpose_to_bf16<<<dim3(DF / 32, D / 32, LAYERS), 256, 0, stream>>>(
        W2, WTall + 2097152, DF, D, (size_t)DF * D, LSTR);

    for (int l = 0; l < LAYERS; ++l) {
        unsigned short* WL = WTall + (size_t)l * LSTR;
        const unsigned short* WqkvT = WL;            // [1536][512]
        const unsigned short* WoT   = WL + 786432;   // [512][512]
        const unsigned short* W1T   = WL + 1048576;  // [2048][512]
        const unsigned short* W2T   = WL + 2097152;  // [512][2048]

        // fused q|k|v projection (elu+1 on q,k), bf16 out: 64x6 blocks
        gemmw<3><<<dim3(M / 128, 1536 / 256), 512, 0, stream>>>(
            x_bf, WqkvT, bq + (size_t)l * D, bk + (size_t)l * D, bv + (size_t)l * D,
            qkv, M, 1536, D);

        attn_stage1<<<dim3(NCHUNK, NH, NB), 256, 0, stream>>>(kb, vb, KVp, zp);
        attn_stage2<<<dim3(NB * NH, 16), 256, 0, stream>>>(KVp, KVb, zp);
        attn_stage3<<<dim3(NCHUNK, NH, NB), 256, 0, stream>>>(qb, kb, vb, KVb, zp, ab);

        // out projection + bf16 residual -> U (f32, plain store)
        gemm8<0, true, false, true, false, 1>
            <<<dim3(M / 128, D / 128), 512, 0, stream>>>(
            ab, WoT, bo + (size_t)l * D, x_bf, U, nullptr, M, D, D);
        // LN1: U -> x_bf ; zero U for W2's atomic accumulate
        ln_u2x<<<dim3(M / 4), 256, 0, stream>>>(U, g1 + (size_t)l * D, be1 + (size_t)l * D, x_bf, 1);

        // FFN: W1 wide-N (64x8 blocks) -> hid bf16
        gemmw<2><<<dim3(M / 128, DF / 256), 512, 0, stream>>>(
            x_bf, W1T, b1 + (size_t)l * DF, nullptr, nullptr, hid, M, DF, D);
        // W2 split-K=2, atomic into zeroed U, residual+bias on kz==0
        gemm8<0, true, true, false, false, 2>
            <<<dim3(M / 128, D / 128, 2), 512, 0, stream>>>(
            hid, W2T, b2 + (size_t)l * D, x_bf, U, nullptr, M, D, DF);
        // LN2: U -> x_bf
        ln_u2x<<<dim3(M / 4), 256, 0, stream>>>(U, g2 + (size_t)l * D, be2 + (size_t)l * D, x_bf, 0);
    }

    ln_final<<<dim3(M / 4), 256, 0, stream>>>(x_bf, gf, bef, (float*)d_out);
}

// Round 14
// 535.502 us; speedup vs baseline: 2.8619x; 1.1223x over previous
//
#include <hip/hip_runtime.h>
#include <hip/hip_bf16.h>
#include <math.h>

#define LAYERS 4
#define DMODEL 512
#define NH 8
#define DH 64
#define DFF 2048
#define NB 4
#define S_LEN 2048
#define MROWS 8192
#define CHUNK 64
#define NCHUNK 32            // S_LEN / CHUNK
#define ATT_EPS 1e-6f
#define LN_EPS 1e-5f
#define SEGSTRIDE (MROWS * DMODEL)   // 4194304 elems per q/k/v segment

typedef __attribute__((ext_vector_type(8))) short short8v;   // 8 bf16
typedef __attribute__((ext_vector_type(4))) float f32x4;

__device__ __forceinline__ float b2f(unsigned short u) {
    union { float f; unsigned u; } c; c.u = ((unsigned)u) << 16; return c.f;
}
__device__ __forceinline__ unsigned short f2b(float f) {
    union { float f; unsigned u; } c; c.f = f;
    unsigned r = c.u + 0x7FFFu + ((c.u >> 16) & 1u);
    return (unsigned short)(r >> 16);
}
__device__ __forceinline__ void gload16(const void* g, void* l) {
    __builtin_amdgcn_global_load_lds(
        (const __attribute__((address_space(1))) void*)g,
        (__attribute__((address_space(3))) void*)l, 16, 0, 0);
}
__device__ __forceinline__ float elu1f(float v) {
    return (v > 0.f) ? (v + 1.f) : __expf(v);
}
__device__ __forceinline__ float geluf(float v) {
    float u = 0.7978845608028654f * v * (1.f + 0.044715f * v * v);
    float th = 1.f - 2.f / (1.f + __expf(2.f * u));
    return 0.5f * v * (1.f + th);
}

// ---------------------------------------------------------------------------
// Wide-N bf16 MFMA GEMM for qkv: BM=128, BN=256, BK=32, 8 waves (2Mx4N)
// each owning 64x64. __launch_bounds__(512,4) (VGPR 128, no spill).
// 2x24KB LDS buffers; counted vmcnt(3); (row>>1)&3 both-sides swizzle.
// ACT==3: qkv-fused (segments of 512: seg<2 elu+1), segmented bf16 out.
// ---------------------------------------------------------------------------
template <int ACT>
__global__ __launch_bounds__(512, 4) void gemmw(
    const unsigned short* __restrict__ A,
    const unsigned short* __restrict__ WT,
    const float* __restrict__ b0, const float* __restrict__ b1,
    const float* __restrict__ b2,
    unsigned short* __restrict__ Cbf,
    int M, int N, int K)
{
    __shared__ short S[2][12288];   // [A 128x32 | B 256x32] swizzled, 24KB/buf

    const int t = threadIdx.x;
    const int m0 = blockIdx.x * 128, n0 = blockIdx.y * 256;
    const int lane = t & 63, wid = t >> 6;
    const int wm = (wid >> 2) * 64;   // 2 M-bands of 64
    const int wn = (wid & 3) * 64;    // 4 N-bands of 64
    const int fr = lane & 15, kg = lane >> 4;

    const unsigned short* gA;
    const unsigned short* gB0;
    const unsigned short* gB1;
    int loA, loB0, loB1;
    {
        const int rowA = t >> 2, spA = t & 3;
        gA = A + (size_t)(m0 + rowA) * K + (spA ^ ((rowA >> 1) & 3)) * 8;
        loA = t * 8;
        const int rB0 = t >> 2, sB0 = t & 3;
        gB0 = WT + (size_t)(n0 + rB0) * K + (sB0 ^ ((rB0 >> 1) & 3)) * 8;
        loB0 = 4096 + t * 8;
        const int u1 = t + 512;
        const int rB1 = u1 >> 2, sB1 = u1 & 3;
        gB1 = WT + (size_t)(n0 + rB1) * K + (sB1 ^ ((rB1 >> 1) & 3)) * 8;
        loB1 = 4096 + u1 * 8;
    }

    int aoff[4], boff[4];
#pragma unroll
    for (int m = 0; m < 4; ++m) {
        const int R = wm + m * 16 + fr;
        aoff[m] = R * 32 + ((kg ^ ((R >> 1) & 3)) << 3);
    }
#pragma unroll
    for (int n = 0; n < 4; ++n) {
        const int R = wn + n * 16 + fr;
        boff[n] = 4096 + R * 32 + ((kg ^ ((R >> 1) & 3)) << 3);
    }

    f32x4 acc[4][4];
#pragma unroll
    for (int m = 0; m < 4; ++m)
#pragma unroll
        for (int n = 0; n < 4; ++n) acc[m][n] = (f32x4){0.f, 0.f, 0.f, 0.f};

#define STAGE(b, kt) do {                                       \
    gload16(gA + (size_t)(kt) * 32, &S[b][loA]);                \
    gload16(gB0 + (size_t)(kt) * 32, &S[b][loB0]);              \
    gload16(gB1 + (size_t)(kt) * 32, &S[b][loB1]); } while (0)

    const int NT = K >> 5;
    STAGE(0, 0);

    for (int td = 0; td < NT; ++td) {
        const int b = td & 1;
        if (td + 1 < NT) {
            STAGE(b ^ 1, td + 1);
            __builtin_amdgcn_sched_barrier(0);
            asm volatile("s_waitcnt vmcnt(3)");   // tile td landed
        } else {
            __builtin_amdgcn_sched_barrier(0);
            asm volatile("s_waitcnt vmcnt(0)");
        }
        __builtin_amdgcn_sched_barrier(0);
        __builtin_amdgcn_s_barrier();
        __builtin_amdgcn_sched_barrier(0);

        short8v af[4], bf[4];
#pragma unroll
        for (int m = 0; m < 4; ++m) af[m] = *(const short8v*)&S[b][aoff[m]];
#pragma unroll
        for (int n = 0; n < 4; ++n) bf[n] = *(const short8v*)&S[b][boff[n]];

        asm volatile("s_waitcnt lgkmcnt(0)");
        __builtin_amdgcn_sched_barrier(0);
        __builtin_amdgcn_s_setprio(1);
#pragma unroll
        for (int m = 0; m < 4; ++m)
#pragma unroll
            for (int n = 0; n < 4; ++n)
                acc[m][n] = __builtin_amdgcn_mfma_f32_16x16x32_bf16(
                    af[m], bf[n], acc[m][n], 0, 0, 0);
        __builtin_amdgcn_s_setprio(0);

        __builtin_amdgcn_sched_barrier(0);
        __builtin_amdgcn_s_barrier();   // protect buf b before restage
    }
#undef STAGE

    const int seg = (ACT == 3) ? (n0 >> 9) : 0;
    const float* bias = (ACT == 3) ? (seg == 0 ? b0 : (seg == 1 ? b1 : b2)) : b0;
    float bv[4];
#pragma unroll
    for (int n = 0; n < 4; ++n) {
        const int col = n0 + wn + n * 16 + fr;
        bv[n] = bias[(ACT == 3) ? (col - seg * 512) : col];
    }

#pragma unroll
    for (int m = 0; m < 4; ++m)
#pragma unroll
        for (int n = 0; n < 4; ++n)
#pragma unroll
            for (int j = 0; j < 4; ++j) {
                const int row = m0 + wm + m * 16 + (lane >> 4) * 4 + j;
                const int col = n0 + wn + n * 16 + fr;
                float v = acc[m][n][j] + bv[n];
                if (ACT == 2) v = geluf(v);
                else if (ACT == 3) { if (seg < 2) v = elu1f(v); }
                if (ACT == 3)
                    Cbf[(size_t)seg * SEGSTRIDE + (size_t)row * 512 + (col - seg * 512)] = f2b(v);
                else
                    Cbf[(size_t)row * N + col] = f2b(v);
            }
}

// ---------------------------------------------------------------------------
// bf16 MFMA GEMM (proven R8/R11 config): 128x128, BK=64, 8 waves (2x4 ->
// 64x32), 2x32KB LDS -> 2 blocks/CU. RESID adds bf16 residual on kz==0;
// WU plain-stores f32 U; WBF16 stores bf16 (kz-segmented when KSPLIT>1).
// ---------------------------------------------------------------------------
template <int ACT, bool RESID, bool WU, bool WBF16, int KSPLIT>
__global__ __launch_bounds__(512, 4) void gemm8(
    const unsigned short* __restrict__ A,
    const unsigned short* __restrict__ WT,
    const float* __restrict__ b0,
    const unsigned short* __restrict__ Xres,
    float* __restrict__ U, unsigned short* __restrict__ Cbf,
    int M, int N, int K)
{
    __shared__ short S[2][16384];

    const int t = threadIdx.x;
    const int m0 = blockIdx.x * 128, n0 = blockIdx.y * 128;
    const int kz = (KSPLIT > 1) ? blockIdx.z : 0;
    const int Kc = K / KSPLIT;
    const int kbeg = kz * Kc;
    const int lane = t & 63, wid = t >> 6;
    const int wm = (wid >> 2) * 64;
    const int wn = (wid & 3) * 32;
    const int fr = lane & 15, kg = lane >> 4;

    const unsigned short* gsrc[4];
    int ldso[4];
#pragma unroll
    for (int r = 0; r < 4; ++r) {
        const int u = (r & 1) ? (t + 512) : t;
        const bool isA = (r < 2);
        const int row = u >> 3, sp = u & 7, sl = sp ^ (row & 7);
        gsrc[r] = (isA ? A + (size_t)(m0 + row) * K
                       : WT + (size_t)(n0 + row) * K) + kbeg + sl * 8;
        ldso[r] = (isA ? 0 : 8192) + u * 8;
    }

    int aoff[2][4], boff[2][2];
#pragma unroll
    for (int h = 0; h < 2; ++h) {
#pragma unroll
        for (int m = 0; m < 4; ++m) {
            const int R = wm + m * 16 + fr;
            aoff[h][m] = R * 64 + (((h * 4 + kg) ^ (R & 7)) * 8);
        }
#pragma unroll
        for (int n = 0; n < 2; ++n) {
            const int R = wn + n * 16 + fr;
            boff[h][n] = 8192 + R * 64 + (((h * 4 + kg) ^ (R & 7)) * 8);
        }
    }

    f32x4 acc[4][2];
#pragma unroll
    for (int m = 0; m < 4; ++m)
#pragma unroll
        for (int n = 0; n < 2; ++n) acc[m][n] = (f32x4){0.f, 0.f, 0.f, 0.f};

#define STAGE(b, kt) do { _Pragma("unroll")                                  \
    for (int r = 0; r < 4; ++r)                                              \
        gload16(gsrc[r] + (size_t)(kt) * 64, &S[b][ldso[r]]); } while (0)

    const int NT = Kc >> 6;
    STAGE(0, 0);

    for (int td = 0; td < NT; ++td) {
        const int b = td & 1;
        if (td + 1 < NT) {
            STAGE(b ^ 1, td + 1);
            __builtin_amdgcn_sched_barrier(0);
            asm volatile("s_waitcnt vmcnt(4)");
        } else {
            __builtin_amdgcn_sched_barrier(0);
            asm volatile("s_waitcnt vmcnt(0)");
        }
        __builtin_amdgcn_sched_barrier(0);
        __builtin_amdgcn_s_barrier();
        __builtin_amdgcn_sched_barrier(0);

        short8v a0[4], b0f[2], a1[4], b1f[2];
#pragma unroll
        for (int m = 0; m < 4; ++m) a0[m] = *(const short8v*)&S[b][aoff[0][m]];
#pragma unroll
        for (int n = 0; n < 2; ++n) b0f[n] = *(const short8v*)&S[b][boff[0][n]];
#pragma unroll
        for (int m = 0; m < 4; ++m) a1[m] = *(const short8v*)&S[b][aoff[1][m]];
#pragma unroll
        for (int n = 0; n < 2; ++n) b1f[n] = *(const short8v*)&S[b][boff[1][n]];

        asm volatile("s_waitcnt lgkmcnt(6)");
        __builtin_amdgcn_sched_barrier(0);
        __builtin_amdgcn_s_setprio(1);
#pragma unroll
        for (int m = 0; m < 4; ++m)
#pragma unroll
            for (int n = 0; n < 2; ++n)
                acc[m][n] = __builtin_amdgcn_mfma_f32_16x16x32_bf16(
                    a0[m], b0f[n], acc[m][n], 0, 0, 0);
        __builtin_amdgcn_s_setprio(0);

        asm volatile("s_waitcnt lgkmcnt(0)");
        __builtin_amdgcn_sched_barrier(0);
        __builtin_amdgcn_s_setprio(1);
#pragma unroll
        for (int m = 0; m < 4; ++m)
#pragma unroll
            for (int n = 0; n < 2; ++n)
                acc[m][n] = __builtin_amdgcn_mfma_f32_16x16x32_bf16(
                    a1[m], b1f[n], acc[m][n], 0, 0, 0);
        __builtin_amdgcn_s_setprio(0);

        __builtin_amdgcn_sched_barrier(0);
        __builtin_amdgcn_s_barrier();
    }
#undef STAGE

    float bv[2];
#pragma unroll
    for (int n = 0; n < 2; ++n)
        bv[n] = b0[n0 + wn + n * 16 + fr];
    if (KSPLIT > 1 && kz != 0) { bv[0] = 0.f; bv[1] = 0.f; }

#pragma unroll
    for (int m = 0; m < 4; ++m)
#pragma unroll
        for (int n = 0; n < 2; ++n)
#pragma unroll
            for (int j = 0; j < 4; ++j) {
                const int row = m0 + wm + m * 16 + (lane >> 4) * 4 + j;
                const int col = n0 + wn + n * 16 + fr;
                float v = acc[m][n][j] + bv[n];
                if (RESID && kz == 0)
                    v += b2f(Xres[(size_t)row * 512 + col]);
                if (ACT == 1) v = elu1f(v);
                else if (ACT == 2) v = geluf(v);
                if (WU)
                    U[(size_t)row * N + col] = v;
                if (WBF16) {
                    if (KSPLIT > 1)
                        Cbf[(size_t)kz * SEGSTRIDE + (size_t)row * N + col] = f2b(v);
                    else
                        Cbf[(size_t)row * N + col] = f2b(v);
                }
            }
}

// ---------------------------------------------------------------------------
// Weight transpose + bf16, batched over layers (blockIdx.z)
// ---------------------------------------------------------------------------
__global__ __launch_bounds__(256) void transpose_to_bf16(
    const float* __restrict__ W, unsigned short* __restrict__ WT, int K, int N,
    size_t wstride, size_t tstride)
{
    __shared__ float tile[32][33];
    const int l = blockIdx.z;
    W += (size_t)l * wstride;
    WT += (size_t)l * tstride;
    const int k0 = blockIdx.x * 32, n0 = blockIdx.y * 32;
    const int tx = threadIdx.x & 31, ty = threadIdx.x >> 5;
#pragma unroll
    for (int i = ty; i < 32; i += 8)
        tile[i][tx] = W[(size_t)(k0 + i) * N + n0 + tx];
    __syncthreads();
#pragma unroll
    for (int i = ty; i < 32; i += 8)
        WT[(size_t)(n0 + i) * K + k0 + tx] = f2b(tile[tx][i]);
}

// input convert: h f32 -> x_bf bf16 only
__global__ __launch_bounds__(256) void cvt_in(
    const float* __restrict__ h, unsigned short* __restrict__ xb, int n)
{
    const int i = (blockIdx.x * 256 + threadIdx.x) * 8;
    if (i >= n) return;
    f32x4 a = *(const f32x4*)(h + i);
    f32x4 b = *(const f32x4*)(h + i + 4);
    short8v p;
    p[0] = f2b(a[0]); p[1] = f2b(a[1]); p[2] = f2b(a[2]); p[3] = f2b(a[3]);
    p[4] = f2b(b[0]); p[5] = f2b(b[1]); p[6] = f2b(b[2]); p[7] = f2b(b[3]);
    *(short8v*)(xb + i) = p;
}

// swizzled 64x64 bf16 tile access: logical (row, sl) -> shorts offset
__device__ __forceinline__ int swzo(int row, int sl) {
    return row * 64 + ((sl ^ (row & 7)) << 3);
}

// ---------------------------------------------------------------------------
// Attention stage 1 (MFMA): per (b,h,chunk) KVt[e][d] = sum_j V[j][e]*K[j][d]
// ---------------------------------------------------------------------------
__global__ __launch_bounds__(256) void attn_stage1(
    const unsigned short* __restrict__ Kf, const unsigned short* __restrict__ Vf,
    unsigned short* __restrict__ KVp, float* __restrict__ zp)
{
    const int c = blockIdx.x, hh = blockIdx.y, bb = blockIdx.z;
    const int t = threadIdx.x;
    const int lane = t & 63, w = t >> 6;
    const int fr = lane & 15, g = lane >> 4;

    __shared__ unsigned short KTs[64 * 72];
    __shared__ unsigned short VTs[64 * 72];

    const size_t rowbase = (size_t)(bb * S_LEN + c * CHUNK);
    const int colbase = hh * DH;

    {
        const int r = lane, cs = w * 16;
        const unsigned short* kp = Kf + (rowbase + r) * DMODEL + colbase + cs;
        const unsigned short* vp = Vf + (rowbase + r) * DMODEL + colbase + cs;
        short8v k0 = *(const short8v*)kp, k1 = *(const short8v*)(kp + 8);
        short8v v0 = *(const short8v*)vp, v1 = *(const short8v*)(vp + 8);
#pragma unroll
        for (int i = 0; i < 8; ++i) {
            KTs[(cs + i) * 72 + r]     = (unsigned short)k0[i];
            KTs[(cs + 8 + i) * 72 + r] = (unsigned short)k1[i];
            VTs[(cs + i) * 72 + r]     = (unsigned short)v0[i];
            VTs[(cs + 8 + i) * 72 + r] = (unsigned short)v1[i];
        }
    }
    __syncthreads();

    f32x4 cacc[4];
#pragma unroll
    for (int nf = 0; nf < 4; ++nf) cacc[nf] = (f32x4){0.f, 0.f, 0.f, 0.f};

    const short8v a0 = *(const short8v*)&VTs[(w * 16 + fr) * 72 + g * 8];
    const short8v a1 = *(const short8v*)&VTs[(w * 16 + fr) * 72 + (4 + g) * 8];
#pragma unroll
    for (int nf = 0; nf < 4; ++nf) {
        short8v bq0 = *(const short8v*)&KTs[(nf * 16 + fr) * 72 + g * 8];
        short8v bq1 = *(const short8v*)&KTs[(nf * 16 + fr) * 72 + (4 + g) * 8];
        cacc[nf] = __builtin_amdgcn_mfma_f32_16x16x32_bf16(a0, bq0, cacc[nf], 0, 0, 0);
        cacc[nf] = __builtin_amdgcn_mfma_f32_16x16x32_bf16(a1, bq1, cacc[nf], 0, 0, 0);
    }

    const size_t base = ((size_t)(bb * NH + hh) * NCHUNK + c) * (DH * DH);
#pragma unroll
    for (int nf = 0; nf < 4; ++nf)
#pragma unroll
        for (int reg = 0; reg < 4; ++reg) {
            const int e = w * 16 + g * 4 + reg;
            const int d = nf * 16 + fr;
            KVp[base + e * 64 + d] = f2b(cacc[nf][reg]);
        }

    if (t < 64) {
        float s = 0.f;
#pragma unroll
        for (int sl = 0; sl < 8; ++sl) {
            short8v kv = *(const short8v*)&KTs[t * 72 + sl * 8];
#pragma unroll
            for (int i = 0; i < 8; ++i) s += b2f((unsigned short)kv[i]);
        }
        zp[((size_t)(bb * NH + hh) * NCHUNK + c) * DH + t] = s;
    }
}

// ---------------------------------------------------------------------------
// Attention stage 2: exclusive prefix over 32 chunk states per (b,h)
// ---------------------------------------------------------------------------
__global__ __launch_bounds__(256) void attn_stage2(
    const unsigned short* __restrict__ KVp, unsigned short* __restrict__ KVb,
    float* __restrict__ zp)
{
    const int bh = blockIdx.x;
    const int e = blockIdx.y * 256 + threadIdx.x;
    const size_t base = (size_t)bh * NCHUNK * (DH * DH) + e;
    float run = 0.f;
#pragma unroll 4
    for (int c = 0; c < NCHUNK; ++c) {
        const float tmp = b2f(KVp[base + (size_t)c * (DH * DH)]);
        KVb[base + (size_t)c * (DH * DH)] = f2b(run);
        run += tmp;
    }
    if (blockIdx.y == 0 && threadIdx.x < DH) {
        float rz = 0.f;
        const size_t zb = (size_t)bh * NCHUNK * DH + threadIdx.x;
#pragma unroll 4
        for (int c = 0; c < NCHUNK; ++c) {
            const float tmp = zp[zb + c * DH];
            zp[zb + c * DH] = rz;
            rz += tmp;
        }
    }
}

// ---------------------------------------------------------------------------
// Attention stage 3 (MFMA)
// ---------------------------------------------------------------------------
__global__ __launch_bounds__(256) void attn_stage3(
    const unsigned short* __restrict__ Qf, const unsigned short* __restrict__ Kf,
    const unsigned short* __restrict__ Vf, const unsigned short* __restrict__ KVb,
    const float* __restrict__ zp, unsigned short* __restrict__ Af)
{
    const int c = blockIdx.x, hh = blockIdx.y, bb = blockIdx.z;
    const int t = threadIdx.x;
    const int lane = t & 63, w = t >> 6;
    const int fr = lane & 15, g = lane >> 4;

    __shared__ unsigned short Qs[4096];
    __shared__ unsigned short Ks[4096];
    __shared__ unsigned short KVts[4096];
    __shared__ unsigned short VTs[64 * 72];
    __shared__ unsigned short Ps[64 * 72];
    __shared__ float zsh[DH];
    __shared__ float den_lds[64];

    const size_t rowbase = (size_t)(bb * S_LEN + c * CHUNK);
    const int colbase = hh * DH;
    const size_t kvbase = ((size_t)(bb * NH + hh) * NCHUNK + c) * (DH * DH);

#pragma unroll
    for (int iss = 0; iss < 2; ++iss) {
        const int u = iss * 256 + t, row = u >> 3, sl = u & 7;
        const int ssl = (sl ^ (row & 7)) * 8;
        gload16(Qf + (rowbase + row) * DMODEL + colbase + ssl, &Qs[(size_t)u * 8]);
        gload16(Kf + (rowbase + row) * DMODEL + colbase + ssl, &Ks[(size_t)u * 8]);
        gload16(KVb + kvbase + row * 64 + ssl, &KVts[(size_t)u * 8]);
    }
    {
        const int r = lane, cs = w * 16;
        const unsigned short* vp = Vf + (rowbase + r) * DMODEL + colbase + cs;
        short8v v0 = *(const short8v*)vp, v1 = *(const short8v*)(vp + 8);
#pragma unroll
        for (int i = 0; i < 8; ++i) {
            VTs[(cs + i) * 72 + r]     = (unsigned short)v0[i];
            VTs[(cs + 8 + i) * 72 + r] = (unsigned short)v1[i];
        }
    }
    if (t < DH) zsh[t] = zp[((size_t)(bb * NH + hh) * NCHUNK + c) * DH + t];
    __syncthreads();

    f32x4 c1[4];
#pragma unroll
    for (int mf = 0; mf < 4; ++mf) c1[mf] = (f32x4){0.f, 0.f, 0.f, 0.f};
    {
        const short8v bq0 = *(const short8v*)&Qs[swzo(w * 16 + fr, g)];
        const short8v bq1 = *(const short8v*)&Qs[swzo(w * 16 + fr, 4 + g)];
#pragma unroll
        for (int mf = 0; mf < 4; ++mf) {
            short8v ak0 = *(const short8v*)&Ks[swzo(mf * 16 + fr, g)];
            short8v ak1 = *(const short8v*)&Ks[swzo(mf * 16 + fr, 4 + g)];
            c1[mf] = __builtin_amdgcn_mfma_f32_16x16x32_bf16(ak0, bq0, c1[mf], 0, 0, 0);
            c1[mf] = __builtin_amdgcn_mfma_f32_16x16x32_bf16(ak1, bq1, c1[mf], 0, 0, 0);
        }
    }

    const int i_my = w * 16 + fr;
    float dint = 0.f;
#pragma unroll
    for (int mf = 0; mf < 4; ++mf)
#pragma unroll
        for (int reg = 0; reg < 4; ++reg) {
            const int j = mf * 16 + g * 4 + reg;
            const float v = (j <= i_my) ? c1[mf][reg] : 0.f;
            dint += v;
            Ps[i_my * 72 + j] = f2b(v);
        }
    dint += __shfl_xor(dint, 16);
    dint += __shfl_xor(dint, 32);

    float dpre = 0.f;
#pragma unroll
    for (int sl = 0; sl < 8; ++sl) {
        short8v qv = *(const short8v*)&Qs[swzo(i_my, sl)];
#pragma unroll
        for (int e = 0; e < 8; ++e) dpre += b2f((unsigned short)qv[e]) * zsh[sl * 8 + e];
    }
    if (g == 0) den_lds[i_my] = dpre + dint + ATT_EPS;

    f32x4 acc[4];
#pragma unroll
    for (int nf = 0; nf < 4; ++nf) acc[nf] = (f32x4){0.f, 0.f, 0.f, 0.f};
    {
        const short8v aq0 = *(const short8v*)&Qs[swzo(w * 16 + fr, g)];
        const short8v aq1 = *(const short8v*)&Qs[swzo(w * 16 + fr, 4 + g)];
#pragma unroll
        for (int nf = 0; nf < 4; ++nf) {
            short8v bkv0 = *(const short8v*)&KVts[swzo(nf * 16 + fr, g)];
            short8v bkv1 = *(const short8v*)&KVts[swzo(nf * 16 + fr, 4 + g)];
            acc[nf] = __builtin_amdgcn_mfma_f32_16x16x32_bf16(aq0, bkv0, acc[nf], 0, 0, 0);
            acc[nf] = __builtin_amdgcn_mfma_f32_16x16x32_bf16(aq1, bkv1, acc[nf], 0, 0, 0);
        }
        const short8v ap0 = *(const short8v*)&Ps[(w * 16 + fr) * 72 + g * 8];
        const short8v ap1 = *(const short8v*)&Ps[(w * 16 + fr) * 72 + (4 + g) * 8];
#pragma unroll
        for (int nf = 0; nf < 4; ++nf) {
            short8v bv0 = *(const short8v*)&VTs[(nf * 16 + fr) * 72 + g * 8];
            short8v bv1 = *(const short8v*)&VTs[(nf * 16 + fr) * 72 + (4 + g) * 8];
            acc[nf] = __builtin_amdgcn_mfma_f32_16x16x32_bf16(ap0, bv0, acc[nf], 0, 0, 0);
            acc[nf] = __builtin_amdgcn_mfma_f32_16x16x32_bf16(ap1, bv1, acc[nf], 0, 0, 0);
        }
    }

#pragma unroll
    for (int reg = 0; reg < 4; ++reg) {
        const int i = w * 16 + g * 4 + reg;
        const float inv = 1.f / den_lds[i];
        unsigned short* dst = Af + (rowbase + i) * DMODEL + colbase;
#pragma unroll
        for (int nf = 0; nf < 4; ++nf)
            dst[nf * 16 + fr] = f2b(acc[nf][reg] * inv);
    }
}

// ---------------------------------------------------------------------------
// LayerNorm: U (f32 pre-LN) -> x_bf (bf16). 4 rows/block.
// ---------------------------------------------------------------------------
__global__ __launch_bounds__(256) void ln_u2x(const float* __restrict__ U,
                                              const float* __restrict__ g,
                                              const float* __restrict__ b,
                                              unsigned short* __restrict__ Xb)
{
    const size_t row = blockIdx.x * 4 + (threadIdx.x >> 6);
    const int t = threadIdx.x & 63;
    const float* ur = U + row * DMODEL;
    f32x4 x0 = *(const f32x4*)&ur[t * 4];
    f32x4 x1 = *(const f32x4*)&ur[256 + t * 4];

    float s  = x0[0] + x0[1] + x0[2] + x0[3] + x1[0] + x1[1] + x1[2] + x1[3];
    float sq = x0[0]*x0[0] + x0[1]*x0[1] + x0[2]*x0[2] + x0[3]*x0[3] +
               x1[0]*x1[0] + x1[1]*x1[1] + x1[2]*x1[2] + x1[3]*x1[3];
#pragma unroll
    for (int m = 1; m < 64; m <<= 1) {
        s  += __shfl_xor(s, m);
        sq += __shfl_xor(sq, m);
    }
    const float mu  = s * (1.f / DMODEL);
    const float var = sq * (1.f / DMODEL) - mu * mu;
    const float rr  = rsqrtf(var + LN_EPS);

    const int c0 = t * 4, c1 = 256 + t * 4;
    f32x4 g0 = *(const f32x4*)&g[c0], g1v = *(const f32x4*)&g[c1];
    f32x4 b0 = *(const f32x4*)&b[c0], b1v = *(const f32x4*)&b[c1];
    unsigned short* xb = Xb + row * DMODEL;
    ushort4 u0, u1;
    u0.x = f2b((x0[0] - mu) * rr * g0[0] + b0[0]);
    u0.y = f2b((x0[1] - mu) * rr * g0[1] + b0[1]);
    u0.z = f2b((x0[2] - mu) * rr * g0[2] + b0[2]);
    u0.w = f2b((x0[3] - mu) * rr * g0[3] + b0[3]);
    u1.x = f2b((x1[0] - mu) * rr * g1v[0] + b1v[0]);
    u1.y = f2b((x1[1] - mu) * rr * g1v[1] + b1v[1]);
    u1.z = f2b((x1[2] - mu) * rr * g1v[2] + b1v[2]);
    u1.w = f2b((x1[3] - mu) * rr * g1v[3] + b1v[3]);
    *(ushort4*)&xb[c0] = u0;
    *(ushort4*)&xb[c1] = u1;
}

// ---------------------------------------------------------------------------
// LayerNorm over two bf16 partial buffers: x = U0b + U1b (split-K halves,
// residual+bias already inside U0b). Writes x_bf. 4 rows/block.
// ---------------------------------------------------------------------------
__global__ __launch_bounds__(256) void ln_2b(const unsigned short* __restrict__ U0b,
                                             const unsigned short* __restrict__ U1b,
                                             const float* __restrict__ g,
                                             const float* __restrict__ b,
                                             unsigned short* __restrict__ Xb)
{
    const size_t row = blockIdx.x * 4 + (threadIdx.x >> 6);
    const int t = threadIdx.x & 63;
    short8v v0 = *(const short8v*)&U0b[row * DMODEL + t * 8];
    short8v v1 = *(const short8v*)&U1b[row * DMODEL + t * 8];
    float x[8];
#pragma unroll
    for (int i = 0; i < 8; ++i)
        x[i] = b2f((unsigned short)v0[i]) + b2f((unsigned short)v1[i]);

    float s = 0.f, sq = 0.f;
#pragma unroll
    for (int i = 0; i < 8; ++i) { s += x[i]; sq += x[i] * x[i]; }
#pragma unroll
    for (int m = 1; m < 64; m <<= 1) {
        s  += __shfl_xor(s, m);
        sq += __shfl_xor(sq, m);
    }
    const float mu  = s * (1.f / DMODEL);
    const float var = sq * (1.f / DMODEL) - mu * mu;
    const float rr  = rsqrtf(var + LN_EPS);

    unsigned short* xb = Xb + row * DMODEL + t * 8;
    short8v p;
#pragma unroll
    for (int i = 0; i < 8; ++i)
        p[i] = f2b((x[i] - mu) * rr * g[t * 8 + i] + b[t * 8 + i]);
    *(short8v*)xb = p;
}

// final LayerNorm: x_bf -> d_out (f32)
__global__ __launch_bounds__(256) void ln_final(const unsigned short* __restrict__ Xb,
                                                const float* __restrict__ g,
                                                const float* __restrict__ b,
                                                float* __restrict__ Out)
{
    const size_t row = blockIdx.x * 4 + (threadIdx.x >> 6);
    const int t = threadIdx.x & 63;
    const unsigned short* xr = Xb + row * DMODEL;
    short8v xv = *(const short8v*)&xr[t * 8];
    float x[8];
#pragma unroll
    for (int i = 0; i < 8; ++i) x[i] = b2f((unsigned short)xv[i]);

    float s = 0.f, sq = 0.f;
#pragma unroll
    for (int i = 0; i < 8; ++i) { s += x[i]; sq += x[i] * x[i]; }
#pragma unroll
    for (int m = 1; m < 64; m <<= 1) {
        s  += __shfl_xor(s, m);
        sq += __shfl_xor(sq, m);
    }
    const float mu  = s * (1.f / DMODEL);
    const float var = sq * (1.f / DMODEL) - mu * mu;
    const float rr  = rsqrtf(var + LN_EPS);

    float* orow = Out + row * DMODEL + t * 8;
    f32x4 o0, o1;
#pragma unroll
    for (int i = 0; i < 4; ++i) {
        o0[i] = (x[i] - mu) * rr * g[t * 8 + i] + b[t * 8 + i];
        o1[i] = (x[4 + i] - mu) * rr * g[t * 8 + 4 + i] + b[t * 8 + 4 + i];
    }
    *(f32x4*)orow = o0;
    *(f32x4*)(orow + 4) = o1;
}

// ---------------------------------------------------------------------------
extern "C" void kernel_launch(void* const* d_in, const int* in_sizes, int n_in,
                              void* d_out, int out_size, void* d_ws, size_t ws_size,
                              hipStream_t stream)
{
    const float* h   = (const float*)d_in[0];
    const float* Wq  = (const float*)d_in[1];
    const float* bq  = (const float*)d_in[2];
    const float* Wk  = (const float*)d_in[3];
    const float* bk  = (const float*)d_in[4];
    const float* Wv  = (const float*)d_in[5];
    const float* bv  = (const float*)d_in[6];
    const float* Wo  = (const float*)d_in[7];
    const float* bo  = (const float*)d_in[8];
    const float* W1  = (const float*)d_in[9];
    const float* b1  = (const float*)d_in[10];
    const float* W2  = (const float*)d_in[11];
    const float* b2  = (const float*)d_in[12];
    const float* g1  = (const float*)d_in[13];
    const float* be1 = (const float*)d_in[14];
    const float* g2  = (const float*)d_in[15];
    const float* be2 = (const float*)d_in[16];
    const float* gf  = (const float*)d_in[17];
    const float* bef = (const float*)d_in[18];

    char* ws = (char*)d_ws;
    const size_t MB = 1024 * 1024;
    unsigned short* x_bf = (unsigned short*)(ws);                 // 8 MB
    unsigned short* qkv  = (unsigned short*)(ws + 8 * MB);        // q|k|v 24 MB
    unsigned short* qb   = qkv;
    unsigned short* kb   = qkv + SEGSTRIDE;
    unsigned short* vb   = qkv + 2 * (size_t)SEGSTRIDE;
    unsigned short* ab   = (unsigned short*)(ws + 32 * MB);       // 8 MB
    unsigned short* hid  = (unsigned short*)(ws + 8 * MB);        // 32 MB alias q|k|v|a
    unsigned short* KVp  = (unsigned short*)(ws + 40 * MB);       // bf16 partials 8 MB
    unsigned short* KVb  = (unsigned short*)(ws + 48 * MB);       // prefix states 8 MB
    float* U             = (float*)(ws + 40 * MB);                // Wo pre-LN f32 16 MB (aliases KVp/KVb)
    unsigned short* U01b = (unsigned short*)(ws + 40 * MB);       // W2 bf16 partial pair 16 MB (same region)
    float* zp            = (float*)(ws + 56 * MB);                // 0.5 MB
    unsigned short* WTall = (unsigned short*)(ws + 57 * MB);      // 24 MB

    const int M = MROWS, D = DMODEL, DF = DFF;
    const size_t LSTR = 3 * 1024 * 1024;

    cvt_in<<<dim3(M * D / (256 * 8)), 256, 0, stream>>>(h, x_bf, M * D);
    transpose_to_bf16<<<dim3(D / 32, D / 32, LAYERS), 256, 0, stream>>>(
        Wq, WTall, D, D, (size_t)D * D, LSTR);
    transpose_to_bf16<<<dim3(D / 32, D / 32, LAYERS), 256, 0, stream>>>(
        Wk, WTall + 262144, D, D, (size_t)D * D, LSTR);
    transpose_to_bf16<<<dim3(D / 32, D / 32, LAYERS), 256, 0, stream>>>(
        Wv, WTall + 524288, D, D, (size_t)D * D, LSTR);
    transpose_to_bf16<<<dim3(D / 32, D / 32, LAYERS), 256, 0, stream>>>(
        Wo, WTall + 786432, D, D, (size_t)D * D, LSTR);
    transpose_to_bf16<<<dim3(D / 32, DF / 32, LAYERS), 256, 0, stream>>>(
        W1, WTall + 1048576, D, DF, (size_t)D * DF, LSTR);
    transpose_to_bf16<<<dim3(DF / 32, D / 32, LAYERS), 256, 0, stream>>>(
        W2, WTall + 2097152, DF, D, (size_t)DF * D, LSTR);

    for (int l = 0; l < LAYERS; ++l) {
        unsigned short* WL = WTall + (size_t)l * LSTR;
        const unsigned short* WqkvT = WL;            // [1536][512]
        const unsigned short* WoT   = WL + 786432;   // [512][512]
        const unsigned short* W1T   = WL + 1048576;  // [2048][512]
        const unsigned short* W2T   = WL + 2097152;  // [512][2048]

        // fused q|k|v projection (elu+1 on q,k), bf16 out: 64x6 blocks
        gemmw<3><<<dim3(M / 128, 1536 / 256), 512, 0, stream>>>(
            x_bf, WqkvT, bq + (size_t)l * D, bk + (size_t)l * D, bv + (size_t)l * D,
            qkv, M, 1536, D);

        attn_stage1<<<dim3(NCHUNK, NH, NB), 256, 0, stream>>>(kb, vb, KVp, zp);
        attn_stage2<<<dim3(NB * NH, 16), 256, 0, stream>>>(KVp, KVb, zp);
        attn_stage3<<<dim3(NCHUNK, NH, NB), 256, 0, stream>>>(qb, kb, vb, KVb, zp, ab);

        // out projection + bf16 residual -> U (f32, plain store)
        gemm8<0, true, true, false, 1>
            <<<dim3(M / 128, D / 128), 512, 0, stream>>>(
            ab, WoT, bo + (size_t)l * D, x_bf, U, nullptr, M, D, D);
        // LN1: U -> x_bf
        ln_u2x<<<dim3(M / 4), 256, 0, stream>>>(U, g1 + (size_t)l * D, be1 + (size_t)l * D, x_bf);

        // FFN: W1 gemm8 (proven 45.9us config, 1024 blocks) -> hid bf16
        gemm8<2, false, false, true, 1>
            <<<dim3(M / 128, DF / 128), 512, 0, stream>>>(
            x_bf, W1T, b1 + (size_t)l * DF, nullptr, nullptr, hid, M, DF, D);
        // W2 split-K=2, deterministic bf16 partial pair (residual+bias in kz0)
        gemm8<0, true, false, true, 2>
            <<<dim3(M / 128, D / 128, 2), 512, 0, stream>>>(
            hid, W2T, b2 + (size_t)l * D, x_bf, nullptr, U01b, M, D, DF);
        // LN2: U0b + U1b -> x_bf
        ln_2b<<<dim3(M / 4), 256, 0, stream>>>(U01b, U01b + SEGSTRIDE,
            g2 + (size_t)l * D, be2 + (size_t)l * D, x_bf);
    }

    ln_final<<<dim3(M / 4), 256, 0, stream>>>(x_bf, gf, bef, (float*)d_out);
}